// Round 1
// baseline (3091.224 us; speedup 1.0000x reference)
//
#include <hip/hip_runtime.h>
#include <hip/hip_bf16.h>
#include <math.h>

#define B_     4
#define SEQ_   1024
#define D_     1024
#define H_     16
#define HD_    64
#define NE_    8      // B_ * TOPK dispatched rows
#define INTER_ 768
#define EPS_   1e-5f

// ---------------- routing: mean over seq, logits, top-2, softmax ----------------
__global__ void route_kernel(const float* __restrict__ hidden, const float* __restrict__ Wr,
                             const float* __restrict__ temp, float* __restrict__ out_logits,
                             int* __restrict__ flat_idx, float* __restrict__ flat_w) {
    __shared__ float col[1024];
    __shared__ float part[1024];
    int b = blockIdx.x;
    int t = threadIdx.x;
    const float* xb = hidden + (size_t)b * SEQ_ * D_;
    float s = 0.f;
    for (int r = 0; r < SEQ_; ++r) s += xb[(size_t)r * D_ + t];
    col[t] = s * (1.0f / SEQ_);
    __syncthreads();
    // 8 experts x 128 threads each
    int j  = t >> 7;
    int d0 = t & 127;
    float p = 0.f;
    for (int d = d0; d < D_; d += 128) p += col[d] * Wr[j * D_ + d];
    part[t] = p;
    __syncthreads();
    for (int off = 64; off >= 1; off >>= 1) {
        if (d0 < off) part[t] += part[t + off];
        __syncthreads();
    }
    if (t == 0) {
        float tc = temp[0];
        tc = fminf(fmaxf(tc, 0.1f), 10.0f);
        float lg[8];
        for (int jj = 0; jj < 8; ++jj) {
            lg[jj] = part[jj * 128] / tc;
            out_logits[b * 8 + jj] = lg[jj];
        }
        // top-2 (ties -> lower index, matches lax.top_k)
        int i0 = 0; float v0 = lg[0];
        for (int jj = 1; jj < 8; ++jj) if (lg[jj] > v0) { v0 = lg[jj]; i0 = jj; }
        int i1 = -1; float v1 = -1e30f;
        for (int jj = 0; jj < 8; ++jj) if (jj != i0 && lg[jj] > v1) { v1 = lg[jj]; i1 = jj; }
        float e1 = expf(v1 - v0);
        float w0 = 1.0f / (1.0f + e1);
        float w1 = e1 / (1.0f + e1);
        flat_idx[2 * b]     = i0;
        flat_idx[2 * b + 1] = i1;
        flat_w[2 * b]       = w0;
        flat_w[2 * b + 1]   = w1;
    }
}

// ---------------- batched fp32 GEMM: C[e] = A[e/aDiv] @ W[flat_idx[e]] ----------------
// M=1024 fixed-multiple-of-128, N mult of 128, K mult of 16
#define BM 128
#define BN 128
#define BK 16

__global__ __launch_bounds__(256) void gemm_moe(const float* __restrict__ Abase,
                                                const float* __restrict__ Wbase,
                                                float* __restrict__ Cbase,
                                                const int* __restrict__ flat_idx,
                                                int M, int N, int K, int aDiv) {
    int e = blockIdx.z;
    const float* A = Abase + (size_t)(e / aDiv) * M * K;
    const float* Wp = Wbase + (size_t)flat_idx[e] * K * N;
    float* C = Cbase + (size_t)e * M * N;
    int m0 = blockIdx.y * BM, n0 = blockIdx.x * BN;

    __shared__ __align__(16) float As[BK][BM + 4];
    __shared__ __align__(16) float Bs[BK][BN + 4];

    int t = threadIdx.x;
    int tx = t & 15, ty = t >> 4;
    float acc[8][8];
#pragma unroll
    for (int i = 0; i < 8; ++i)
#pragma unroll
        for (int jj = 0; jj < 8; ++jj) acc[i][jj] = 0.f;

    for (int k0 = 0; k0 < K; k0 += BK) {
        // A tile: 128 rows x 16 cols (store transposed)
#pragma unroll
        for (int L = t; L < 512; L += 256) {
            int row = L >> 2, seg = L & 3;
            const float4 a4 = *(const float4*)&A[(size_t)(m0 + row) * K + k0 + seg * 4];
            As[seg * 4 + 0][row] = a4.x;
            As[seg * 4 + 1][row] = a4.y;
            As[seg * 4 + 2][row] = a4.z;
            As[seg * 4 + 3][row] = a4.w;
        }
        // B tile: 16 rows x 128 cols
#pragma unroll
        for (int L = t; L < 512; L += 256) {
            int row = L >> 5, c4 = L & 31;
            *(float4*)&Bs[row][c4 * 4] = *(const float4*)&Wp[(size_t)(k0 + row) * N + n0 + c4 * 4];
        }
        __syncthreads();
#pragma unroll
        for (int kk = 0; kk < BK; ++kk) {
            float4 a0 = *(const float4*)&As[kk][ty * 8];
            float4 a1 = *(const float4*)&As[kk][ty * 8 + 4];
            float4 b0 = *(const float4*)&Bs[kk][tx * 8];
            float4 b1 = *(const float4*)&Bs[kk][tx * 8 + 4];
            float av[8] = {a0.x, a0.y, a0.z, a0.w, a1.x, a1.y, a1.z, a1.w};
            float bv[8] = {b0.x, b0.y, b0.z, b0.w, b1.x, b1.y, b1.z, b1.w};
#pragma unroll
            for (int i = 0; i < 8; ++i)
#pragma unroll
                for (int jj = 0; jj < 8; ++jj) acc[i][jj] += av[i] * bv[jj];
        }
        __syncthreads();
    }
#pragma unroll
    for (int i = 0; i < 8; ++i) {
        size_t roff = (size_t)(m0 + ty * 8 + i) * N + n0 + tx * 8;
        *(float4*)&C[roff]     = make_float4(acc[i][0], acc[i][1], acc[i][2], acc[i][3]);
        *(float4*)&C[roff + 4] = make_float4(acc[i][4], acc[i][5], acc[i][6], acc[i][7]);
    }
}

// ---------------- RoPE (in-place on q,k parts of qkv) ----------------
__global__ void rope_kernel(float* __restrict__ qkv, const float* __restrict__ cosb,
                            const float* __restrict__ sinb) {
    int idx = blockIdx.x * 256 + threadIdx.x;  // e,s,qk,h,d(32)
    int d  = idx & 31;
    int h  = (idx >> 5) & 15;
    int qk = (idx >> 9) & 1;
    int s  = (idx >> 10) & 1023;
    int e  = idx >> 20;
    float* p = qkv + ((size_t)e * SEQ_ + s) * 3072 + qk * 1024 + h * 64;
    float x1 = p[d], x2 = p[d + 32];
    float c1 = cosb[s * 64 + d],      s1 = sinb[s * 64 + d];
    float c2 = cosb[s * 64 + d + 32], s2 = sinb[s * 64 + d + 32];
    p[d]      = x1 * c1 - x2 * s1;
    p[d + 32] = x2 * c2 + x1 * s2;
}

// ---------------- flash-style attention ----------------
// grid (SEQ/32, H, NE); block 256. Q tile 32, K tile 64.
__global__ __launch_bounds__(256) void attn_kernel(const float* __restrict__ qkv,
                                                   float* __restrict__ ctx) {
    int qt = blockIdx.x, h = blockIdx.y, e = blockIdx.z;
    const float* base = qkv + (size_t)e * SEQ_ * 3072;
    const float* Qg = base + h * 64;
    const float* Kg = base + 1024 + h * 64;
    const float* Vg = base + 2048 + h * 64;

    __shared__ float Qs[32][65];
    __shared__ float Ks[64][65];
    __shared__ float Vs[64][65];
    __shared__ float Ps[32][65];
    __shared__ float mrow[32], lrow[32], arow[32];
    __shared__ float red[8][32];

    int t = threadIdx.x;
    int r = t & 31, g = t >> 5;

    for (int L = t; L < 2048; L += 256) {
        int row = L >> 6, d = L & 63;
        Qs[row][d] = Qg[(size_t)(qt * 32 + row) * 3072 + d] * 0.125f;
    }
    if (t < 32) { mrow[t] = -1e30f; lrow[t] = 0.f; }
    float acc[8] = {0.f, 0.f, 0.f, 0.f, 0.f, 0.f, 0.f, 0.f};
    __syncthreads();

    for (int kt = 0; kt < 16; ++kt) {
        for (int L = t; L < 4096; L += 256) {
            int row = L >> 6, d = L & 63;
            Ks[row][d] = Kg[(size_t)(kt * 64 + row) * 3072 + d];
            Vs[row][d] = Vg[(size_t)(kt * 64 + row) * 3072 + d];
        }
        __syncthreads();

        float sc[8] = {0.f, 0.f, 0.f, 0.f, 0.f, 0.f, 0.f, 0.f};
        for (int d = 0; d < 64; ++d) {
            float qv = Qs[r][d];
#pragma unroll
            for (int jj = 0; jj < 8; ++jj) sc[jj] += qv * Ks[g * 8 + jj][d];
        }
        float lm = sc[0];
#pragma unroll
        for (int jj = 1; jj < 8; ++jj) lm = fmaxf(lm, sc[jj]);
        red[g][r] = lm;
        __syncthreads();
        if (g == 0) {
            float nm = mrow[r];
            for (int gg = 0; gg < 8; ++gg) nm = fmaxf(nm, red[gg][r]);
            arow[r] = __expf(mrow[r] - nm);
            mrow[r] = nm;
        }
        __syncthreads();
        float m = mrow[r];
        float ps = 0.f;
#pragma unroll
        for (int jj = 0; jj < 8; ++jj) {
            float pv = __expf(sc[jj] - m);
            Ps[r][g * 8 + jj] = pv;
            ps += pv;
        }
        red[g][r] = ps;
        __syncthreads();
        if (g == 0) {
            float ssum = 0.f;
            for (int gg = 0; gg < 8; ++gg) ssum += red[gg][r];
            lrow[r] = lrow[r] * arow[r] + ssum;
        }
        __syncthreads();
        float alpha = arow[r];
#pragma unroll
        for (int i = 0; i < 8; ++i) acc[i] *= alpha;
        for (int kk = 0; kk < 64; ++kk) {
            float pv = Ps[r][kk];
#pragma unroll
            for (int i = 0; i < 8; ++i) acc[i] += pv * Vs[kk][g * 8 + i];
        }
        __syncthreads();
    }
    float linv = 1.0f / lrow[r];
    float* co = ctx + ((size_t)e * SEQ_ + qt * 32 + r) * D_ + h * 64 + g * 8;
    float4 o0 = make_float4(acc[0] * linv, acc[1] * linv, acc[2] * linv, acc[3] * linv);
    float4 o1 = make_float4(acc[4] * linv, acc[5] * linv, acc[6] * linv, acc[7] * linv);
    *(float4*)&co[0] = o0;
    *(float4*)&co[4] = o1;
}

// ---------------- xn = rmsnorm(hidden[b] + attn_out) ----------------
__global__ void add_rmsnorm_kernel(const float* __restrict__ hidden, const float* __restrict__ ao,
                                   float* __restrict__ xn) {
    int row = blockIdx.x;          // e*SEQ + s
    int e = row >> 10;
    int b = e >> 1;
    int s = row & 1023;
    const float* xr = hidden + (((size_t)b * SEQ_ + s) << 10);
    const float* ar = ao + ((size_t)row << 10);
    float* o = xn + ((size_t)row << 10);
    int t = threadIdx.x;
    float v[4];
    float ss = 0.f;
#pragma unroll
    for (int i = 0; i < 4; ++i) {
        v[i] = xr[t + i * 256] + ar[t + i * 256];
        ss += v[i] * v[i];
    }
    for (int off = 32; off >= 1; off >>= 1) ss += __shfl_down(ss, off, 64);
    __shared__ float wred[4];
    if ((t & 63) == 0) wred[t >> 6] = ss;
    __syncthreads();
    float tot = wred[0] + wred[1] + wred[2] + wred[3];
    float scale = rsqrtf(tot * (1.0f / 1024.0f) + EPS_);
#pragma unroll
    for (int i = 0; i < 4; ++i) o[t + i * 256] = v[i] * scale;
}

// ---------------- act = silu(gate) * up ----------------
__global__ void silu_mul_kernel(const float* __restrict__ gu, float* __restrict__ act) {
    int idx = blockIdx.x * 256 + threadIdx.x;   // NE*SEQ*INTER
    int col = idx % INTER_;
    int rowi = idx / INTER_;
    const float* row = gu + (size_t)rowi * (2 * INTER_);
    float gt = row[col], u = row[col + INTER_];
    float sg = gt / (1.0f + __expf(-gt));
    act[idx] = sg * u;
}

// ---------------- out[b] = sum_j w_e * rmsnorm(xn[e] + mlp[e]) ----------------
__global__ void final_kernel(const float* __restrict__ xn, const float* __restrict__ mlp,
                             const float* __restrict__ flat_w, float* __restrict__ out) {
    int row = blockIdx.x;           // b*SEQ + s
    int b = row >> 10;
    int s = row & 1023;
    int t = threadIdx.x;
    __shared__ float wred[4];
    float res[4] = {0.f, 0.f, 0.f, 0.f};
    for (int j = 0; j < 2; ++j) {
        int e = 2 * b + j;
        size_t off = (((size_t)e * SEQ_ + s) << 10);
        const float* xr = xn + off;
        const float* mr = mlp + off;
        float v[4];
        float ss = 0.f;
#pragma unroll
        for (int i = 0; i < 4; ++i) {
            v[i] = xr[t + i * 256] + mr[t + i * 256];
            ss += v[i] * v[i];
        }
        for (int off2 = 32; off2 >= 1; off2 >>= 1) ss += __shfl_down(ss, off2, 64);
        if ((t & 63) == 0) wred[t >> 6] = ss;
        __syncthreads();
        float tot = wred[0] + wred[1] + wred[2] + wred[3];
        float scale = rsqrtf(tot * (1.0f / 1024.0f) + EPS_);
        float w = flat_w[e];
#pragma unroll
        for (int i = 0; i < 4; ++i) res[i] += w * v[i] * scale;
        __syncthreads();   // WAR: wred reused next j
    }
    float* o = out + ((size_t)row << 10);
#pragma unroll
    for (int i = 0; i < 4; ++i) o[t + i * 256] = res[i];
}

extern "C" void kernel_launch(void* const* d_in, const int* in_sizes, int n_in,
                              void* d_out, int out_size, void* d_ws, size_t ws_size,
                              hipStream_t stream) {
    const float* hidden = (const float*)d_in[0];
    const float* cosb   = (const float*)d_in[1];
    const float* sinb   = (const float*)d_in[2];
    const float* Wr     = (const float*)d_in[3];
    const float* temp   = (const float*)d_in[4];
    const float* Wqkv   = (const float*)d_in[5];
    const float* Wo     = (const float*)d_in[6];
    const float* Wgu    = (const float*)d_in[7];
    const float* Wd     = (const float*)d_in[8];
    float* out = (float*)d_out;

    float* wsf = (float*)d_ws;
    int*   flat_idx = (int*)d_ws;         // ints [0..7]
    float* flat_w   = wsf + 8;            // floats [8..15]
    float* R1 = wsf + 256;                // 25,165,824 f  (qkv -> attn_out -> gu -> mlp_out)
    float* R2 = R1 + 25165824;            // 8,388,608 f   (ctx -> act)
    float* R3 = R2 + 8388608;             // 8,388,608 f   (xn)

    float* out_logits = out + (size_t)B_ * SEQ_ * D_;

    // 1) routing
    route_kernel<<<B_, 1024, 0, stream>>>(hidden, Wr, temp, out_logits, flat_idx, flat_w);

    // 2) qkv = x @ Wqkv[idx]   (A batch = e/2 -> hidden sample)
    gemm_moe<<<dim3(3072 / BN, 1024 / BM, NE_), 256, 0, stream>>>(
        hidden, Wqkv, R1, flat_idx, 1024, 3072, 1024, 2);

    // 3) RoPE in place
    rope_kernel<<<(NE_ * SEQ_ * 2 * H_ * 32) / 256, 256, 0, stream>>>(R1, cosb, sinb);

    // 4) attention -> ctx (R2)
    attn_kernel<<<dim3(SEQ_ / 32, H_, NE_), 256, 0, stream>>>(R1, R2);

    // 5) attn_out = ctx @ Wo[idx] -> R1 (qkv dead)
    gemm_moe<<<dim3(1024 / BN, 1024 / BM, NE_), 256, 0, stream>>>(
        R2, Wo, R1, flat_idx, 1024, 1024, 1024, 1);

    // 6) xn = rmsnorm(hidden[b] + attn_out) -> R3
    add_rmsnorm_kernel<<<NE_ * SEQ_, 256, 0, stream>>>(hidden, R1, R3);

    // 7) gu = xn @ Wgu[idx] -> R1
    gemm_moe<<<dim3(1536 / BN, 1024 / BM, NE_), 256, 0, stream>>>(
        R3, Wgu, R1, flat_idx, 1024, 1536, 1024, 1);

    // 8) act = silu(gate)*up -> R2
    silu_mul_kernel<<<(NE_ * SEQ_ * INTER_) / 256, 256, 0, stream>>>(R1, R2);

    // 9) mlp_out = act @ Wd[idx] -> R1
    gemm_moe<<<dim3(1024 / BN, 1024 / BM, NE_), 256, 0, stream>>>(
        R2, Wd, R1, flat_idx, 1024, 1024, 768, 1);

    // 10) out = sum_e w_e * rmsnorm(xn + mlp_out)
    final_kernel<<<B_ * SEQ_, 256, 0, stream>>>(R3, R1, flat_w, out);
}

// Round 2
// 699.179 us; speedup vs baseline: 4.4212x; 4.4212x over previous
//
#include <hip/hip_runtime.h>
#include <hip/hip_bf16.h>
#include <math.h>

#define B_     4
#define SEQ_   1024
#define D_     1024
#define H_     16
#define NE_    8
#define INTER_ 768
#define EPS_   1e-5f

typedef unsigned short u16;
typedef __attribute__((ext_vector_type(8))) short s8v;      // 8 bf16 (4 VGPRs) - MFMA A/B frag
typedef __attribute__((ext_vector_type(4))) float f4v;      // MFMA C/D frag
typedef __attribute__((ext_vector_type(4))) unsigned short u16x4;
typedef __attribute__((ext_vector_type(8))) unsigned short u16x8;

__device__ __forceinline__ u16 f2bf(float x) {
    union { float f; unsigned u; } c; c.f = x;
    unsigned r = (c.u + 0x7FFFu + ((c.u >> 16) & 1u)) >> 16;
    return (u16)r;
}
__device__ __forceinline__ float bf2f(u16 h) {
    union { unsigned u; float f; } c; c.u = ((unsigned)h) << 16;
    return c.f;
}

// async global->LDS, 16B per lane; lds ptr must be wave-uniform (HW adds lane*16)
#define GLDS16(gp, lp) \
    __builtin_amdgcn_global_load_lds((const __attribute__((address_space(1))) unsigned int*)(gp), \
                                     (__attribute__((address_space(3))) unsigned int*)(lp), 16, 0, 0)

// ---------------- routing ----------------
__global__ void route_kernel(const float* __restrict__ hidden, const float* __restrict__ Wr,
                             const float* __restrict__ temp, float* __restrict__ out_logits,
                             int* __restrict__ flat_idx, float* __restrict__ flat_w) {
    __shared__ float col[1024];
    __shared__ float part[1024];
    int b = blockIdx.x;
    int t = threadIdx.x;
    const float* xb = hidden + (size_t)b * SEQ_ * D_;
    float s = 0.f;
    for (int r = 0; r < SEQ_; ++r) s += xb[(size_t)r * D_ + t];
    col[t] = s * (1.0f / SEQ_);
    __syncthreads();
    int j  = t >> 7;
    int d0 = t & 127;
    float p = 0.f;
    for (int d = d0; d < D_; d += 128) p += col[d] * Wr[j * D_ + d];
    part[t] = p;
    __syncthreads();
    for (int off = 64; off >= 1; off >>= 1) {
        if (d0 < off) part[t] += part[t + off];
        __syncthreads();
    }
    if (t == 0) {
        float tc = temp[0];
        tc = fminf(fmaxf(tc, 0.1f), 10.0f);
        float lg[8];
        for (int jj = 0; jj < 8; ++jj) {
            lg[jj] = part[jj * 128] / tc;
            out_logits[b * 8 + jj] = lg[jj];
        }
        int i0 = 0; float v0 = lg[0];
        for (int jj = 1; jj < 8; ++jj) if (lg[jj] > v0) { v0 = lg[jj]; i0 = jj; }
        int i1 = -1; float v1 = -1e30f;
        for (int jj = 0; jj < 8; ++jj) if (jj != i0 && lg[jj] > v1) { v1 = lg[jj]; i1 = jj; }
        float e1 = expf(v1 - v0);
        flat_idx[2 * b]     = i0;
        flat_idx[2 * b + 1] = i1;
        flat_w[2 * b]       = 1.0f / (1.0f + e1);
        flat_w[2 * b + 1]   = e1 / (1.0f + e1);
    }
}

// ---------------- weight transpose+cast: W[e][K][N] f32 -> Wt[e][N][K] bf16 ----------------
__global__ __launch_bounds__(256) void wtrans(const float* __restrict__ W, u16* __restrict__ Wt,
                                              int K, int N) {
    __shared__ float tile[32][33];
    int e = blockIdx.z;
    int k0 = blockIdx.y * 32, n0 = blockIdx.x * 32;
    const float* Wp = W + (size_t)e * K * N;
    u16* Wtp = Wt + (size_t)e * K * N;
    int t = threadIdx.x;
    int r = t >> 3, cs = t & 7;
    float4 v = *(const float4*)&Wp[(size_t)(k0 + r) * N + n0 + cs * 4];
    tile[r][cs * 4 + 0] = v.x;
    tile[r][cs * 4 + 1] = v.y;
    tile[r][cs * 4 + 2] = v.z;
    tile[r][cs * 4 + 3] = v.w;
    __syncthreads();
    u16x4 o;
#pragma unroll
    for (int jj = 0; jj < 4; ++jj) o[jj] = f2bf(tile[cs * 4 + jj][r]);
    *(u16x4*)&Wtp[(size_t)(n0 + r) * K + k0 + cs * 4] = o;
}

// ---------------- cast hidden f32 -> bf16 ----------------
__global__ void cast_hidden(const float* __restrict__ x, u16* __restrict__ xb) {
    size_t i = (size_t)blockIdx.x * 256 + threadIdx.x;
    float4 v = *(const float4*)&x[i * 4];
    u16x4 o = {f2bf(v.x), f2bf(v.y), f2bf(v.z), f2bf(v.w)};
    *(u16x4*)&xb[i * 4] = o;
}

// ---------------- bf16 MFMA GEMM (m97 pattern): C[e] = A[e/aDiv] @ Wt[flat_idx[e]]^T ----------------
// A: [M][K] bf16 k-contig; Wt: [N][K] bf16 k-contig; C: [M][N] (fp32 or bf16)
template<int OUTBF>
__global__ __launch_bounds__(256) void gemm_bf16(const u16* __restrict__ Abase,
                                                 const u16* __restrict__ Wtbase,
                                                 void* __restrict__ Cb,
                                                 const int* __restrict__ flat_idx,
                                                 int M, int N, int K, int aDiv) {
    __shared__ __align__(16) u16 As[128 * 32];
    __shared__ __align__(16) u16 Bs[128 * 32];
    int e = blockIdx.z;
    const u16* A  = Abase + (size_t)(e / aDiv) * M * K;
    const u16* Wt = Wtbase + (size_t)flat_idx[e] * N * K;
    int m0 = blockIdx.y * 128, n0 = blockIdx.x * 128;
    int t = threadIdx.x, lane = t & 63, w = t >> 6;
    int g = lane >> 4, c = lane & 15;
    int wm = (w >> 1) * 64, wn = (w & 1) * 64;

    f4v acc[4][4];
#pragma unroll
    for (int i = 0; i < 4; ++i)
#pragma unroll
        for (int jj = 0; jj < 4; ++jj) acc[i][jj] = (f4v){0.f, 0.f, 0.f, 0.f};

    for (int k0 = 0; k0 < K; k0 += 32) {
#pragma unroll
        for (int it = 0; it < 2; ++it) {
            int p = it * 256 + w * 64 + lane;
            int row = p >> 2, seg = p & 3;
            GLDS16(A  + (size_t)(m0 + row) * K + k0 + seg * 8, As + (size_t)(it * 256 + w * 64) * 8);
            GLDS16(Wt + (size_t)(n0 + row) * K + k0 + seg * 8, Bs + (size_t)(it * 256 + w * 64) * 8);
        }
        __syncthreads();
        s8v af[4], bfr[4];
#pragma unroll
        for (int ti = 0; ti < 4; ++ti) af[ti]  = *(const s8v*)&As[(wm + ti * 16 + c) * 32 + g * 8];
#pragma unroll
        for (int tj = 0; tj < 4; ++tj) bfr[tj] = *(const s8v*)&Bs[(wn + tj * 16 + c) * 32 + g * 8];
#pragma unroll
        for (int ti = 0; ti < 4; ++ti)
#pragma unroll
            for (int tj = 0; tj < 4; ++tj)
                acc[ti][tj] = __builtin_amdgcn_mfma_f32_16x16x32_bf16(af[ti], bfr[tj], acc[ti][tj], 0, 0, 0);
        __syncthreads();
    }
    // C/D layout: col=lane&15, row=(lane>>4)*4+reg
    if (OUTBF) {
        u16* C = (u16*)Cb + (size_t)e * M * N;
#pragma unroll
        for (int ti = 0; ti < 4; ++ti)
#pragma unroll
            for (int tj = 0; tj < 4; ++tj)
#pragma unroll
                for (int i = 0; i < 4; ++i)
                    C[(size_t)(m0 + wm + ti * 16 + g * 4 + i) * N + n0 + wn + tj * 16 + c] = f2bf(acc[ti][tj][i]);
    } else {
        float* C = (float*)Cb + (size_t)e * M * N;
#pragma unroll
        for (int ti = 0; ti < 4; ++ti)
#pragma unroll
            for (int tj = 0; tj < 4; ++tj)
#pragma unroll
                for (int i = 0; i < 4; ++i)
                    C[(size_t)(m0 + wm + ti * 16 + g * 4 + i) * N + n0 + wn + tj * 16 + c] = acc[ti][tj][i];
    }
}

// ---------------- RoPE + split cast: qkvb bf16 -> Qb, Kb bf16 ----------------
__global__ void rope_cast(const u16* __restrict__ qkvb, const float* __restrict__ cosb,
                          const float* __restrict__ sinb, u16* __restrict__ Qb, u16* __restrict__ Kb) {
    int idx = blockIdx.x * 256 + threadIdx.x;
    int d = idx & 31, h = (idx >> 5) & 15, s = (idx >> 9) & 1023, e = idx >> 19;
    size_t base = ((size_t)(e * 1024) + s) * 3072 + h * 64;
    size_t ob   = ((size_t)(e * 1024) + s) * 1024 + h * 64;
    float c1 = cosb[s * 64 + d],      s1 = sinb[s * 64 + d];
    float c2 = cosb[s * 64 + d + 32], s2 = sinb[s * 64 + d + 32];
    float q1 = bf2f(qkvb[base + d]), q2 = bf2f(qkvb[base + d + 32]);
    Qb[ob + d]      = f2bf(q1 * c1 - q2 * s1);
    Qb[ob + d + 32] = f2bf(q2 * c2 + q1 * s2);
    float k1 = bf2f(qkvb[base + 1024 + d]), k2 = bf2f(qkvb[base + 1024 + d + 32]);
    Kb[ob + d]      = f2bf(k1 * c1 - k2 * s1);
    Kb[ob + d + 32] = f2bf(k2 * c2 + k1 * s2);
}

// ---------------- V transpose: qkvb v-part -> Vtg[e][h][d=64][kv=1024] bf16 ----------------
__global__ __launch_bounds__(256) void vtrans(const u16* __restrict__ qkvb, u16* __restrict__ Vtg) {
    __shared__ __align__(16) u16 tile[64 * 72];
    int s0 = blockIdx.x * 64;
    int eh = blockIdx.y;
    int e = eh >> 4, h = eh & 15;
    int t = threadIdx.x;
#pragma unroll
    for (int it = 0; it < 2; ++it) {
        int p = it * 256 + t;
        int sr = p >> 3, ds = p & 7;
        u16x8 v = *(const u16x8*)&qkvb[((size_t)(e * 1024) + s0 + sr) * 3072 + 2048 + h * 64 + ds * 8];
        *(u16x8*)&tile[sr * 72 + ds * 8] = v;
    }
    __syncthreads();
#pragma unroll
    for (int it = 0; it < 2; ++it) {
        int p = it * 256 + t;
        int d = p >> 3, ks = p & 7;
        u16x8 o;
#pragma unroll
        for (int jj = 0; jj < 8; ++jj) o[jj] = tile[(ks * 8 + jj) * 72 + d];
        *(u16x8*)&Vtg[((size_t)((e * 16 + h) * 64) + d) * 1024 + s0 + ks * 8] = o;
    }
}

// ---------------- MFMA flash attention ----------------
// grid (16 qtiles, 16 h, 8 e), block 256 (4 waves, 16 q-rows each). K/V tile = 64.
// LDS seg placement XOR-swizzled (permuted at the global-fetch side).
__global__ __launch_bounds__(256) void attn_mfma(const u16* __restrict__ Qb, const u16* __restrict__ Kb,
                                                 const u16* __restrict__ Vtg, u16* __restrict__ ctx) {
    __shared__ __align__(16) u16 Ks[64 * 64];     // [kv][dseg^: stored seg ss holds d-seg ss^(kv&7)]
    __shared__ __align__(16) u16 Vt[64 * 64];     // [d][kvseg^: stored seg ss holds kv-seg ss^(d&7)]
    __shared__ __align__(16) u16 Ps[4 * 16 * 72]; // per-wave P tile, rows padded to 72 shorts (144B)
    int qt = blockIdx.x, h = blockIdx.y, e = blockIdx.z;
    int t = threadIdx.x, lane = t & 63, w = t >> 6;
    int g = lane >> 4, c = lane & 15;
    int q0 = qt * 64 + w * 16;
    u16* PsW = Ps + w * 16 * 72;

    // preload Q A-frags (A: row=lane&15, k=(lane>>4)*8+j)
    s8v qf[2];
#pragma unroll
    for (int ks = 0; ks < 2; ++ks)
        qf[ks] = *(const s8v*)&Qb[((size_t)(e * 1024) + q0 + c) * 1024 + h * 64 + ks * 32 + g * 8];

    f4v O[4];
#pragma unroll
    for (int tj = 0; tj < 4; ++tj) O[tj] = (f4v){0.f, 0.f, 0.f, 0.f};
    float mi[4] = {-1e30f, -1e30f, -1e30f, -1e30f};
    float li[4] = {0.f, 0.f, 0.f, 0.f};

    for (int kt = 0; kt < 16; ++kt) {
#pragma unroll
        for (int it = 0; it < 2; ++it) {
            int p = it * 256 + w * 64 + lane;
            int kv = p >> 3, ss = p & 7;
            GLDS16(Kb + ((size_t)(e * 1024 + kt * 64 + kv)) * 1024 + h * 64 + (ss ^ (kv & 7)) * 8,
                   Ks + (size_t)(it * 256 + w * 64) * 8);
            int d = kv;
            GLDS16(Vtg + ((size_t)((e * 16 + h) * 64 + d)) * 1024 + kt * 64 + (ss ^ (d & 7)) * 8,
                   Vt + (size_t)(it * 256 + w * 64) * 8);
        }
        __syncthreads();

        // S = Q K^T (B-frag: col=lane&15 -> kv, k=d)
        f4v st[4];
#pragma unroll
        for (int tj = 0; tj < 4; ++tj) st[tj] = (f4v){0.f, 0.f, 0.f, 0.f};
#pragma unroll
        for (int ks = 0; ks < 2; ++ks)
#pragma unroll
            for (int tj = 0; tj < 4; ++tj) {
                int kv = tj * 16 + c;
                s8v kf = *(const s8v*)&Ks[kv * 64 + (((ks * 4 + g) ^ (kv & 7)) * 8)];
                st[tj] = __builtin_amdgcn_mfma_f32_16x16x32_bf16(qf[ks], kf, st[tj], 0, 0, 0);
            }
#pragma unroll
        for (int tj = 0; tj < 4; ++tj)
#pragma unroll
            for (int i = 0; i < 4; ++i) st[tj][i] *= 0.125f;

        // online softmax; row = g*4+i lives in the 16 lanes sharing g -> shfl_xor over low 4 bits
        float pv[4][4], al[4];
#pragma unroll
        for (int i = 0; i < 4; ++i) {
            float mx = fmaxf(fmaxf(st[0][i], st[1][i]), fmaxf(st[2][i], st[3][i]));
#pragma unroll
            for (int msk = 1; msk <= 8; msk <<= 1) mx = fmaxf(mx, __shfl_xor(mx, msk, 64));
            float mnew = fmaxf(mi[i], mx);
            al[i] = __expf(mi[i] - mnew);
            mi[i] = mnew;
            float s = 0.f;
#pragma unroll
            for (int tj = 0; tj < 4; ++tj) { float p = __expf(st[tj][i] - mnew); pv[tj][i] = p; s += p; }
#pragma unroll
            for (int msk = 1; msk <= 8; msk <<= 1) s += __shfl_xor(s, msk, 64);
            li[i] = li[i] * al[i] + s;
        }
#pragma unroll
        for (int tj = 0; tj < 4; ++tj)
#pragma unroll
            for (int i = 0; i < 4; ++i) PsW[(g * 4 + i) * 72 + tj * 16 + c] = f2bf(pv[tj][i]);
#pragma unroll
        for (int tj = 0; tj < 4; ++tj)
#pragma unroll
            for (int i = 0; i < 4; ++i) O[tj][i] *= al[i];

        // O += P V (A-frag from Ps, B-frag from Vt)
#pragma unroll
        for (int ks = 0; ks < 2; ++ks) {
            s8v pf = *(const s8v*)&PsW[c * 72 + ks * 32 + g * 8];
#pragma unroll
            for (int tj = 0; tj < 4; ++tj) {
                int d = tj * 16 + c;
                s8v vf = *(const s8v*)&Vt[d * 64 + (((ks * 4 + g) ^ (d & 7)) * 8)];
                O[tj] = __builtin_amdgcn_mfma_f32_16x16x32_bf16(pf, vf, O[tj], 0, 0, 0);
            }
        }
        __syncthreads();
    }
#pragma unroll
    for (int i = 0; i < 4; ++i) {
        float inv = 1.0f / li[i];
        size_t rbase = ((size_t)(e * 1024) + q0 + g * 4 + i) * 1024 + h * 64;
#pragma unroll
        for (int tj = 0; tj < 4; ++tj) ctx[rbase + tj * 16 + c] = f2bf(O[tj][i] * inv);
    }
}

// ---------------- xnb = bf16(rmsnorm(hidden[b] + attn_out)) ----------------
__global__ void add_rmsnorm(const float* __restrict__ hidden, const float* __restrict__ ao,
                            u16* __restrict__ xnb) {
    int row = blockIdx.x;          // e*SEQ + s
    int e = row >> 10;
    int b = e >> 1;
    int s = row & 1023;
    const float* xr = hidden + (((size_t)b * SEQ_ + s) << 10);
    const float* ar = ao + ((size_t)row << 10);
    u16* o = xnb + ((size_t)row << 10);
    int t = threadIdx.x;
    float v[4];
    float ss = 0.f;
#pragma unroll
    for (int i = 0; i < 4; ++i) {
        v[i] = xr[t + i * 256] + ar[t + i * 256];
        ss += v[i] * v[i];
    }
    for (int off = 32; off >= 1; off >>= 1) ss += __shfl_down(ss, off, 64);
    __shared__ float wred[4];
    if ((t & 63) == 0) wred[t >> 6] = ss;
    __syncthreads();
    float tot = wred[0] + wred[1] + wred[2] + wred[3];
    float scale = rsqrtf(tot * (1.0f / 1024.0f) + EPS_);
#pragma unroll
    for (int i = 0; i < 4; ++i) o[t + i * 256] = f2bf(v[i] * scale);
}

// ---------------- act = silu(gate) * up  (bf16 in/out) ----------------
__global__ void silu_mul(const u16* __restrict__ gub, u16* __restrict__ act) {
    int col = blockIdx.x * 256 + threadIdx.x;
    int row = blockIdx.y;
    float gt = bf2f(gub[(size_t)row * 1536 + col]);
    float u  = bf2f(gub[(size_t)row * 1536 + 768 + col]);
    act[(size_t)row * 768 + col] = f2bf(gt / (1.f + __expf(-gt)) * u);
}

// ---------------- out[b] = sum_j w_e * rmsnorm(xn[e] + mlp[e]) ----------------
__global__ void final_kernel(const u16* __restrict__ xnb, const float* __restrict__ mlp,
                             const float* __restrict__ flat_w, float* __restrict__ out) {
    int row = blockIdx.x;           // b*SEQ + s
    int b = row >> 10;
    int s = row & 1023;
    int t = threadIdx.x;
    __shared__ float wred[4];
    float res[4] = {0.f, 0.f, 0.f, 0.f};
    for (int j = 0; j < 2; ++j) {
        int e = 2 * b + j;
        size_t off = (((size_t)e * SEQ_ + s) << 10);
        const u16* xr = xnb + off;
        const float* mr = mlp + off;
        float v[4];
        float ss = 0.f;
#pragma unroll
        for (int i = 0; i < 4; ++i) {
            v[i] = bf2f(xr[t + i * 256]) + mr[t + i * 256];
            ss += v[i] * v[i];
        }
        for (int off2 = 32; off2 >= 1; off2 >>= 1) ss += __shfl_down(ss, off2, 64);
        if ((t & 63) == 0) wred[t >> 6] = ss;
        __syncthreads();
        float tot = wred[0] + wred[1] + wred[2] + wred[3];
        float scale = rsqrtf(tot * (1.0f / 1024.0f) + EPS_);
        float wgt = flat_w[e];
#pragma unroll
        for (int i = 0; i < 4; ++i) res[i] += wgt * v[i] * scale;
        __syncthreads();
    }
    float* o = out + ((size_t)row << 10);
#pragma unroll
    for (int i = 0; i < 4; ++i) o[t + i * 256] = res[i];
}

extern "C" void kernel_launch(void* const* d_in, const int* in_sizes, int n_in,
                              void* d_out, int out_size, void* d_ws, size_t ws_size,
                              hipStream_t stream) {
    const float* hidden = (const float*)d_in[0];
    const float* cosb   = (const float*)d_in[1];
    const float* sinb   = (const float*)d_in[2];
    const float* Wr     = (const float*)d_in[3];
    const float* temp   = (const float*)d_in[4];
    const float* Wqkv   = (const float*)d_in[5];
    const float* Wo     = (const float*)d_in[6];
    const float* Wgu    = (const float*)d_in[7];
    const float* Wd     = (const float*)d_in[8];
    float* out = (float*)d_out;
    float* out_logits = out + (size_t)B_ * SEQ_ * D_;

    char* base = (char*)d_ws;
    int*   flat_idx = (int*)base;
    float* flat_w   = (float*)(base + 128);
    size_t off = 1024;
    u16* WqkvT = (u16*)(base + off); off += (size_t)8 * 3072 * 1024 * 2;
    u16* WoT   = (u16*)(base + off); off += (size_t)8 * 1024 * 1024 * 2;
    u16* WguT  = (u16*)(base + off); off += (size_t)8 * 1536 * 1024 * 2;
    u16* WdT   = (u16*)(base + off); off += (size_t)8 * 1024 * 768 * 2;
    u16* hb    = (u16*)(base + off); off += (size_t)4 * 1024 * 1024 * 2;
    u16* qkvb  = (u16*)(base + off); off += (size_t)8 * 1024 * 3072 * 2;
    u16* Qb    = (u16*)(base + off); off += (size_t)8 * 1024 * 1024 * 2;
    u16* Kb    = (u16*)(base + off); off += (size_t)8 * 1024 * 1024 * 2;
    u16* Vtg   = (u16*)(base + off); off += (size_t)8 * 1024 * 1024 * 2;
    u16* ctxb  = (u16*)(base + off); off += (size_t)8 * 1024 * 1024 * 2;
    float* R1  = (float*)(base + off); off += (size_t)8 * 1024 * 1024 * 4;
    u16* xnb   = (u16*)(base + off); off += (size_t)8 * 1024 * 1024 * 2;
    // qkvb is dead after rope_cast+vtrans -> overlay gub/act there
    u16* gub   = qkvb;
    u16* actb  = qkvb + (size_t)8 * 1024 * 1536;

    route_kernel<<<B_, 1024, 0, stream>>>(hidden, Wr, temp, out_logits, flat_idx, flat_w);
    cast_hidden<<<4096, 256, 0, stream>>>(hidden, hb);
    wtrans<<<dim3(96, 32, 8), 256, 0, stream>>>(Wqkv, WqkvT, 1024, 3072);
    wtrans<<<dim3(32, 32, 8), 256, 0, stream>>>(Wo, WoT, 1024, 1024);
    wtrans<<<dim3(48, 32, 8), 256, 0, stream>>>(Wgu, WguT, 1024, 1536);
    wtrans<<<dim3(32, 24, 8), 256, 0, stream>>>(Wd, WdT, 768, 1024);

    gemm_bf16<1><<<dim3(24, 8, 8), 256, 0, stream>>>(hb, WqkvT, qkvb, flat_idx, 1024, 3072, 1024, 2);
    rope_cast<<<16384, 256, 0, stream>>>(qkvb, cosb, sinb, Qb, Kb);
    vtrans<<<dim3(16, 128), 256, 0, stream>>>(qkvb, Vtg);
    attn_mfma<<<dim3(16, 16, 8), 256, 0, stream>>>(Qb, Kb, Vtg, ctxb);
    gemm_bf16<0><<<dim3(8, 8, 8), 256, 0, stream>>>(ctxb, WoT, R1, flat_idx, 1024, 1024, 1024, 1);
    add_rmsnorm<<<NE_ * SEQ_, 256, 0, stream>>>(hidden, R1, xnb);
    gemm_bf16<1><<<dim3(12, 8, 8), 256, 0, stream>>>(xnb, WguT, gub, flat_idx, 1024, 1536, 1024, 1);
    silu_mul<<<dim3(3, 8192), 256, 0, stream>>>(gub, actb);
    gemm_bf16<0><<<dim3(8, 8, 8), 256, 0, stream>>>(actb, WdT, R1, flat_idx, 1024, 1024, 768, 1);
    final_kernel<<<B_ * SEQ_, 256, 0, stream>>>(xnb, R1, flat_w, out);
}

// Round 3
// 591.095 us; speedup vs baseline: 5.2297x; 1.1829x over previous
//
#include <hip/hip_runtime.h>
#include <hip/hip_bf16.h>
#include <math.h>

#define B_     4
#define SEQ_   1024
#define D_     1024
#define H_     16
#define NE_    8
#define INTER_ 768
#define EPS_   1e-5f

typedef unsigned short u16;
typedef __attribute__((ext_vector_type(8))) short s8v;      // 8 bf16 (4 VGPRs) - MFMA A/B frag (x32)
typedef __attribute__((ext_vector_type(4))) short s4v;      // 4 bf16 (2 VGPRs) - MFMA A/B frag (x16)
typedef __attribute__((ext_vector_type(4))) float f4v;      // MFMA C/D frag
typedef __attribute__((ext_vector_type(4))) unsigned short u16x4;
typedef __attribute__((ext_vector_type(8))) unsigned short u16x8;

__device__ __forceinline__ u16 f2bf(float x) {
    union { float f; unsigned u; } c; c.f = x;
    unsigned r = (c.u + 0x7FFFu + ((c.u >> 16) & 1u)) >> 16;
    return (u16)r;
}
__device__ __forceinline__ float bf2f(u16 h) {
    union { unsigned u; float f; } c; c.u = ((unsigned)h) << 16;
    return c.f;
}
// pack two floats to packed bf16 (round-half-up in magnitude, ~0.5ulp)
__device__ __forceinline__ unsigned pk2(float a, float b) {
    union { float f; unsigned u; } x, y; x.f = a; y.f = b;
    return ((x.u + 0x8000u) >> 16) | ((y.u + 0x8000u) & 0xffff0000u);
}

// async global->LDS, 16B per lane; lds ptr must be wave-uniform (HW adds lane*16)
#define GLDS16(gp, lp) \
    __builtin_amdgcn_global_load_lds((const __attribute__((address_space(1))) unsigned int*)(gp), \
                                     (__attribute__((address_space(3))) unsigned int*)(lp), 16, 0, 0)

// ---------------- routing, 2-stage ----------------
__global__ void route1(const float* __restrict__ hidden, float* __restrict__ part) {
    int b = blockIdx.x, ch = blockIdx.y, t = threadIdx.x;
    const float* xb = hidden + (size_t)b * SEQ_ * D_ + (size_t)ch * 32 * D_;
    float4 acc = make_float4(0.f, 0.f, 0.f, 0.f);
    for (int r = 0; r < 32; ++r) {
        float4 v = *(const float4*)&xb[(size_t)r * D_ + t * 4];
        acc.x += v.x; acc.y += v.y; acc.z += v.z; acc.w += v.w;
    }
    *(float4*)&part[((size_t)(b * 32 + ch)) * D_ + t * 4] = acc;
}

__global__ void route2(const float* __restrict__ part, const float* __restrict__ Wr,
                       const float* __restrict__ temp, float* __restrict__ out_logits,
                       int* __restrict__ flat_idx, float* __restrict__ flat_w) {
    __shared__ float col[1024];
    __shared__ float sm[8];
    int b = blockIdx.x, t = threadIdx.x;
    float4 s = make_float4(0.f, 0.f, 0.f, 0.f);
    for (int ch = 0; ch < 32; ++ch) {
        float4 v = *(const float4*)&part[((size_t)(b * 32 + ch)) * D_ + t * 4];
        s.x += v.x; s.y += v.y; s.z += v.z; s.w += v.w;
    }
    col[t * 4 + 0] = s.x * (1.f / 1024.f);
    col[t * 4 + 1] = s.y * (1.f / 1024.f);
    col[t * 4 + 2] = s.z * (1.f / 1024.f);
    col[t * 4 + 3] = s.w * (1.f / 1024.f);
    __syncthreads();
    int j = t >> 5, d0 = t & 31;
    float p = 0.f;
    for (int d = d0; d < 1024; d += 32) p += col[d] * Wr[j * 1024 + d];
    for (int off = 16; off >= 1; off >>= 1) p += __shfl_down(p, off, 32);
    if (d0 == 0) sm[j] = p;
    __syncthreads();
    if (t == 0) {
        float tc = temp[0];
        tc = fminf(fmaxf(tc, 0.1f), 10.0f);
        float lg[8];
        for (int jj = 0; jj < 8; ++jj) {
            lg[jj] = sm[jj] / tc;
            out_logits[b * 8 + jj] = lg[jj];
        }
        int i0 = 0; float v0 = lg[0];
        for (int jj = 1; jj < 8; ++jj) if (lg[jj] > v0) { v0 = lg[jj]; i0 = jj; }
        int i1 = -1; float v1 = -1e30f;
        for (int jj = 0; jj < 8; ++jj) if (jj != i0 && lg[jj] > v1) { v1 = lg[jj]; i1 = jj; }
        float e1 = expf(v1 - v0);
        flat_idx[2 * b]     = i0;
        flat_idx[2 * b + 1] = i1;
        flat_w[2 * b]       = 1.0f / (1.0f + e1);
        flat_w[2 * b + 1]   = e1 / (1.0f + e1);
    }
}

// ---------------- weight transpose+cast: W[e][K][N] f32 -> Wt[e][N][K] bf16, 64x64 tiles ----------------
__global__ __launch_bounds__(256) void wtrans(const float* __restrict__ W, u16* __restrict__ Wt,
                                              int K, int N) {
    __shared__ float tile[64][65];
    int e = blockIdx.z;
    int k0 = blockIdx.y * 64, n0 = blockIdx.x * 64;
    const float* Wp = W + (size_t)e * K * N;
    u16* Wtp = Wt + (size_t)e * K * N;
    int t = threadIdx.x;
    int kk = t >> 4, ns = t & 15;
#pragma unroll
    for (int p = 0; p < 4; ++p) {
        float4 v = *(const float4*)&Wp[(size_t)(k0 + kk + p * 16) * N + n0 + ns * 4];
        tile[kk + p * 16][ns * 4 + 0] = v.x;
        tile[kk + p * 16][ns * 4 + 1] = v.y;
        tile[kk + p * 16][ns * 4 + 2] = v.z;
        tile[kk + p * 16][ns * 4 + 3] = v.w;
    }
    __syncthreads();
    int nn = t >> 3, ks = t & 7;
#pragma unroll
    for (int p = 0; p < 2; ++p) {
        u16x8 o;
#pragma unroll
        for (int jj = 0; jj < 8; ++jj) o[jj] = f2bf(tile[ks * 8 + jj][nn + p * 32]);
        *(u16x8*)&Wtp[(size_t)(n0 + nn + p * 32) * K + k0 + ks * 8] = o;
    }
}

// ---------------- cast hidden f32 -> bf16 ----------------
__global__ void cast_hidden(const float* __restrict__ x, u16* __restrict__ xb) {
    size_t i = (size_t)blockIdx.x * 256 + threadIdx.x;
    float4 v = *(const float4*)&x[i * 4];
    u16x4 o = {f2bf(v.x), f2bf(v.y), f2bf(v.z), f2bf(v.w)};
    *(u16x4*)&xb[i * 4] = o;
}

// ---------------- bf16 MFMA GEMM (m97 pattern) ----------------
template<int OUTBF>
__global__ __launch_bounds__(256) void gemm_bf16(const u16* __restrict__ Abase,
                                                 const u16* __restrict__ Wtbase,
                                                 void* __restrict__ Cb,
                                                 const int* __restrict__ flat_idx,
                                                 int M, int N, int K, int aDiv) {
    __shared__ __align__(16) u16 As[128 * 32];
    __shared__ __align__(16) u16 Bs[128 * 32];
    int e = blockIdx.z;
    const u16* A  = Abase + (size_t)(e / aDiv) * M * K;
    const u16* Wt = Wtbase + (size_t)flat_idx[e] * N * K;
    int m0 = blockIdx.y * 128, n0 = blockIdx.x * 128;
    int t = threadIdx.x, lane = t & 63, w = t >> 6;
    int g = lane >> 4, c = lane & 15;
    int wm = (w >> 1) * 64, wn = (w & 1) * 64;

    f4v acc[4][4];
#pragma unroll
    for (int i = 0; i < 4; ++i)
#pragma unroll
        for (int jj = 0; jj < 4; ++jj) acc[i][jj] = (f4v){0.f, 0.f, 0.f, 0.f};

    for (int k0 = 0; k0 < K; k0 += 32) {
#pragma unroll
        for (int it = 0; it < 2; ++it) {
            int p = it * 256 + w * 64 + lane;
            int row = p >> 2, seg = p & 3;
            GLDS16(A  + (size_t)(m0 + row) * K + k0 + seg * 8, As + (size_t)(it * 256 + w * 64) * 8);
            GLDS16(Wt + (size_t)(n0 + row) * K + k0 + seg * 8, Bs + (size_t)(it * 256 + w * 64) * 8);
        }
        __syncthreads();
        s8v af[4], bfr[4];
#pragma unroll
        for (int ti = 0; ti < 4; ++ti) af[ti]  = *(const s8v*)&As[(wm + ti * 16 + c) * 32 + g * 8];
#pragma unroll
        for (int tj = 0; tj < 4; ++tj) bfr[tj] = *(const s8v*)&Bs[(wn + tj * 16 + c) * 32 + g * 8];
#pragma unroll
        for (int ti = 0; ti < 4; ++ti)
#pragma unroll
            for (int tj = 0; tj < 4; ++tj)
                acc[ti][tj] = __builtin_amdgcn_mfma_f32_16x16x32_bf16(af[ti], bfr[tj], acc[ti][tj], 0, 0, 0);
        __syncthreads();
    }
    if (OUTBF) {
        u16* C = (u16*)Cb + (size_t)e * M * N;
#pragma unroll
        for (int ti = 0; ti < 4; ++ti)
#pragma unroll
            for (int tj = 0; tj < 4; ++tj)
#pragma unroll
                for (int i = 0; i < 4; ++i)
                    C[(size_t)(m0 + wm + ti * 16 + g * 4 + i) * N + n0 + wn + tj * 16 + c] = f2bf(acc[ti][tj][i]);
    } else {
        float* C = (float*)Cb + (size_t)e * M * N;
#pragma unroll
        for (int ti = 0; ti < 4; ++ti)
#pragma unroll
            for (int tj = 0; tj < 4; ++tj)
#pragma unroll
                for (int i = 0; i < 4; ++i)
                    C[(size_t)(m0 + wm + ti * 16 + g * 4 + i) * N + n0 + wn + tj * 16 + c] = acc[ti][tj][i];
    }
}

// ---------------- RoPE + split cast (vectorized); Q gets 0.125*log2(e) folded in ----------------
__global__ void rope_cast(const u16* __restrict__ qkvb, const float* __restrict__ cosb,
                          const float* __restrict__ sinb, u16* __restrict__ Qb, u16* __restrict__ Kb) {
    int idx = blockIdx.x * 256 + threadIdx.x;   // bits: seg(2) h(4) s(10) e(3)
    int seg = idx & 3, h = (idx >> 2) & 15, s = (idx >> 6) & 1023, e = idx >> 16;
    int d0 = seg * 8;
    size_t base = ((size_t)(e * 1024) + s) * 3072 + h * 64;
    size_t ob   = ((size_t)(e * 1024) + s) * 1024 + h * 64;
    u16x8 qlo = *(const u16x8*)&qkvb[base + d0];
    u16x8 qhi = *(const u16x8*)&qkvb[base + d0 + 32];
    u16x8 klo = *(const u16x8*)&qkvb[base + 1024 + d0];
    u16x8 khi = *(const u16x8*)&qkvb[base + 1024 + d0 + 32];
    float c1[8], c2[8], s1[8], s2[8];
    *(float4*)&c1[0] = *(const float4*)&cosb[s * 64 + d0];
    *(float4*)&c1[4] = *(const float4*)&cosb[s * 64 + d0 + 4];
    *(float4*)&c2[0] = *(const float4*)&cosb[s * 64 + d0 + 32];
    *(float4*)&c2[4] = *(const float4*)&cosb[s * 64 + d0 + 36];
    *(float4*)&s1[0] = *(const float4*)&sinb[s * 64 + d0];
    *(float4*)&s1[4] = *(const float4*)&sinb[s * 64 + d0 + 4];
    *(float4*)&s2[0] = *(const float4*)&sinb[s * 64 + d0 + 32];
    *(float4*)&s2[4] = *(const float4*)&sinb[s * 64 + d0 + 36];
    const float SQ = 0.125f * 1.44269504f;  // fold score scale + log2e into Q
    u16x8 qol, qoh, kol, koh;
#pragma unroll
    for (int jj = 0; jj < 8; ++jj) {
        float q1 = bf2f(qlo[jj]), q2 = bf2f(qhi[jj]);
        qol[jj] = f2bf((q1 * c1[jj] - q2 * s1[jj]) * SQ);
        qoh[jj] = f2bf((q2 * c2[jj] + q1 * s2[jj]) * SQ);
        float k1 = bf2f(klo[jj]), k2 = bf2f(khi[jj]);
        kol[jj] = f2bf(k1 * c1[jj] - k2 * s1[jj]);
        koh[jj] = f2bf(k2 * c2[jj] + k1 * s2[jj]);
    }
    *(u16x8*)&Qb[ob + d0]      = qol;
    *(u16x8*)&Qb[ob + d0 + 32] = qoh;
    *(u16x8*)&Kb[ob + d0]      = kol;
    *(u16x8*)&Kb[ob + d0 + 32] = koh;
}

// ---------------- V transpose: qkvb v-part -> Vtg[e][h][d=64][kv=1024] bf16 ----------------
__global__ __launch_bounds__(256) void vtrans(const u16* __restrict__ qkvb, u16* __restrict__ Vtg) {
    __shared__ __align__(16) u16 tile[64 * 72];
    int s0 = blockIdx.x * 64;
    int eh = blockIdx.y;
    int e = eh >> 4, h = eh & 15;
    int t = threadIdx.x;
#pragma unroll
    for (int it = 0; it < 2; ++it) {
        int p = it * 256 + t;
        int sr = p >> 3, ds = p & 7;
        u16x8 v = *(const u16x8*)&qkvb[((size_t)(e * 1024) + s0 + sr) * 3072 + 2048 + h * 64 + ds * 8];
        *(u16x8*)&tile[sr * 72 + ds * 8] = v;
    }
    __syncthreads();
#pragma unroll
    for (int it = 0; it < 2; ++it) {
        int p = it * 256 + t;
        int d = p >> 3, ks = p & 7;
        u16x8 o;
#pragma unroll
        for (int jj = 0; jj < 8; ++jj) o[jj] = tile[(ks * 8 + jj) * 72 + d];
        *(u16x8*)&Vtg[((size_t)((e * 16 + h) * 64) + d) * 1024 + s0 + ks * 8] = o;
    }
}

// ---------------- MFMA flash attention v2: S^T = K Q^T, P feeds PV from registers ----------------
// grid (8 e, 16 h, 16 qt) -> all qt-blocks of one (e,h) land on one XCD (id%8 = e).
// block 256 = 4 waves, each wave: 16 q rows, full 64-kv tile. No online max (scores are O(1)).
__global__ __launch_bounds__(256) void attn_mfma(const u16* __restrict__ Qb, const u16* __restrict__ Kb,
                                                 const u16* __restrict__ Vtg, u16* __restrict__ ctx) {
    __shared__ __align__(16) u16 Ks[64 * 64];   // [kv][d-seg swizzled: stored seg ss = data seg ss^(kv&7)]
    __shared__ __align__(16) u16 Vt[64 * 64];   // [d][kv-seg swizzled: stored seg ss = data seg ss^(d&7)]
    int e = blockIdx.x, h = blockIdx.y, qt = blockIdx.z;
    int t = threadIdx.x, lane = t & 63, w = t >> 6;
    int g = lane >> 4, c = lane & 15;
    int q0 = qt * 64 + w * 16;

    // Q as B-operand frag (n=q=c, k=d=ks*32+g*8+j); Qb is pre-scaled by 0.125*log2e
    s8v qf[2];
#pragma unroll
    for (int ks = 0; ks < 2; ++ks)
        qf[ks] = *(const s8v*)&Qb[((size_t)(e * 1024) + q0 + c) * 1024 + h * 64 + ks * 32 + g * 8];

    f4v O[4];
#pragma unroll
    for (int tj = 0; tj < 4; ++tj) O[tj] = (f4v){0.f, 0.f, 0.f, 0.f};
    f4v liacc = (f4v){0.f, 0.f, 0.f, 0.f};
    const s4v vone = {(short)0x3F80, (short)0x3F80, (short)0x3F80, (short)0x3F80};  // bf16 1.0

    for (int kt = 0; kt < 16; ++kt) {
#pragma unroll
        for (int it = 0; it < 2; ++it) {
            int p = it * 256 + w * 64 + lane;
            int row = p >> 3, ss = p & 7;
            GLDS16(Kb + ((size_t)(e * 1024 + kt * 64 + row)) * 1024 + h * 64 + (ss ^ (row & 7)) * 8,
                   Ks + (size_t)(it * 256 + w * 64) * 8);
            GLDS16(Vtg + ((size_t)((e * 16 + h) * 64 + row)) * 1024 + kt * 64 + (ss ^ (row & 7)) * 8,
                   Vt + (size_t)(it * 256 + w * 64) * 8);
        }
        __syncthreads();

        // S^T[kv][q]: A = K (m=kv=tj*16+c, k=d), B = Q. C rows = kv = g*4+i, cols = q = c.
        f4v st[4];
#pragma unroll
        for (int tj = 0; tj < 4; ++tj) st[tj] = (f4v){0.f, 0.f, 0.f, 0.f};
#pragma unroll
        for (int ks = 0; ks < 2; ++ks)
#pragma unroll
            for (int tj = 0; tj < 4; ++tj) {
                int kvl = tj * 16 + c;
                s8v kf = *(const s8v*)&Ks[kvl * 64 + (((ks * 4 + g) ^ (kvl & 7)) * 8)];
                st[tj] = __builtin_amdgcn_mfma_f32_16x16x32_bf16(kf, qf[ks], st[tj], 0, 0, 0);
            }

        // P^T = exp2(S^T) -> pack straight into 16x16x16 A-frags (k = g*4+j == C-row g*4+i)
        s4v pf[4];
#pragma unroll
        for (int tj = 0; tj < 4; ++tj) {
            float p0 = __builtin_amdgcn_exp2f(st[tj][0]);
            float p1 = __builtin_amdgcn_exp2f(st[tj][1]);
            float p2 = __builtin_amdgcn_exp2f(st[tj][2]);
            float p3 = __builtin_amdgcn_exp2f(st[tj][3]);
            union { unsigned u[2]; s4v v; } pu;
            pu.u[0] = pk2(p0, p1);
            pu.u[1] = pk2(p2, p3);
            pf[tj] = pu.v;
        }

        // O[q][d] += P V : A = P (m=q, k=kv chunk 16), B = V^T (n=d=tjd*16+c, k=kv)
        // li via ones-column MFMA: lands in O's row layout (row=q=g*4+i) - no shuffles needed.
#pragma unroll
        for (int tjC = 0; tjC < 4; ++tjC) {
            liacc = __builtin_amdgcn_mfma_f32_16x16x16bf16_1k(pf[tjC], vone, liacc, 0, 0, 0);
#pragma unroll
            for (int tjd = 0; tjd < 4; ++tjd) {
                int d = tjd * 16 + c;
                int sd = tjC * 2 + (g >> 1);
                s4v vf = *(const s4v*)&Vt[d * 64 + ((sd ^ (d & 7)) * 8) + (g & 1) * 4];
                O[tjd] = __builtin_amdgcn_mfma_f32_16x16x16bf16_1k(pf[tjC], vf, O[tjd], 0, 0, 0);
            }
        }
        __syncthreads();
    }
#pragma unroll
    for (int i = 0; i < 4; ++i) {
        float linv = 1.0f / liacc[i];
        size_t rbase = ((size_t)(e * 1024) + q0 + g * 4 + i) * 1024 + h * 64;
#pragma unroll
        for (int tjd = 0; tjd < 4; ++tjd)
            ctx[rbase + tjd * 16 + c] = f2bf(O[tjd][i] * linv);
    }
}

// ---------------- xnb = bf16(rmsnorm(hidden[b] + attn_out)) ----------------
__global__ void add_rmsnorm(const float* __restrict__ hidden, const float* __restrict__ ao,
                            u16* __restrict__ xnb) {
    int row = blockIdx.x;          // e*SEQ + s
    int e = row >> 10;
    int b = e >> 1;
    int s = row & 1023;
    const float* xr = hidden + (((size_t)b * SEQ_ + s) << 10);
    const float* ar = ao + ((size_t)row << 10);
    u16* o = xnb + ((size_t)row << 10);
    int t = threadIdx.x;
    float v[4];
    float ss = 0.f;
#pragma unroll
    for (int i = 0; i < 4; ++i) {
        v[i] = xr[t + i * 256] + ar[t + i * 256];
        ss += v[i] * v[i];
    }
    for (int off = 32; off >= 1; off >>= 1) ss += __shfl_down(ss, off, 64);
    __shared__ float wred[4];
    if ((t & 63) == 0) wred[t >> 6] = ss;
    __syncthreads();
    float tot = wred[0] + wred[1] + wred[2] + wred[3];
    float scale = rsqrtf(tot * (1.0f / 1024.0f) + EPS_);
#pragma unroll
    for (int i = 0; i < 4; ++i) o[t + i * 256] = f2bf(v[i] * scale);
}

// ---------------- act = silu(gate) * up  (bf16, vectorized x8) ----------------
__global__ void silu_mul(const u16* __restrict__ gub, u16* __restrict__ act) {
    int idx = blockIdx.x * 256 + threadIdx.x;    // row*96 + col8
    int col8 = idx % 96;
    int row  = idx / 96;
    u16x8 gv = *(const u16x8*)&gub[(size_t)row * 1536 + col8 * 8];
    u16x8 uv = *(const u16x8*)&gub[(size_t)row * 1536 + 768 + col8 * 8];
    u16x8 o;
#pragma unroll
    for (int jj = 0; jj < 8; ++jj) {
        float gt = bf2f(gv[jj]), u = bf2f(uv[jj]);
        o[jj] = f2bf(gt / (1.f + __expf(-gt)) * u);
    }
    *(u16x8*)&act[(size_t)row * 768 + col8 * 8] = o;
}

// ---------------- out[b] = sum_j w_e * rmsnorm(xn[e] + mlp[e]) ----------------
__global__ void final_kernel(const u16* __restrict__ xnb, const float* __restrict__ mlp,
                             const float* __restrict__ flat_w, float* __restrict__ out) {
    int row = blockIdx.x;           // b*SEQ + s
    int b = row >> 10;
    int s = row & 1023;
    int t = threadIdx.x;
    __shared__ float wred[4];
    float res[4] = {0.f, 0.f, 0.f, 0.f};
    for (int j = 0; j < 2; ++j) {
        int e = 2 * b + j;
        size_t off = (((size_t)e * SEQ_ + s) << 10);
        const u16* xr = xnb + off;
        const float* mr = mlp + off;
        float v[4];
        float ss = 0.f;
#pragma unroll
        for (int i = 0; i < 4; ++i) {
            v[i] = bf2f(xr[t + i * 256]) + mr[t + i * 256];
            ss += v[i] * v[i];
        }
        for (int off2 = 32; off2 >= 1; off2 >>= 1) ss += __shfl_down(ss, off2, 64);
        if ((t & 63) == 0) wred[t >> 6] = ss;
        __syncthreads();
        float tot = wred[0] + wred[1] + wred[2] + wred[3];
        float scale = rsqrtf(tot * (1.0f / 1024.0f) + EPS_);
        float wgt = flat_w[e];
#pragma unroll
        for (int i = 0; i < 4; ++i) res[i] += wgt * v[i] * scale;
        __syncthreads();
    }
    float* o = out + ((size_t)row << 10);
#pragma unroll
    for (int i = 0; i < 4; ++i) o[t + i * 256] = res[i];
}

extern "C" void kernel_launch(void* const* d_in, const int* in_sizes, int n_in,
                              void* d_out, int out_size, void* d_ws, size_t ws_size,
                              hipStream_t stream) {
    const float* hidden = (const float*)d_in[0];
    const float* cosb   = (const float*)d_in[1];
    const float* sinb   = (const float*)d_in[2];
    const float* Wr     = (const float*)d_in[3];
    const float* temp   = (const float*)d_in[4];
    const float* Wqkv   = (const float*)d_in[5];
    const float* Wo     = (const float*)d_in[6];
    const float* Wgu    = (const float*)d_in[7];
    const float* Wd     = (const float*)d_in[8];
    float* out = (float*)d_out;
    float* out_logits = out + (size_t)B_ * SEQ_ * D_;

    char* base = (char*)d_ws;
    int*   flat_idx = (int*)base;
    float* flat_w   = (float*)(base + 128);
    float* routeP   = (float*)(base + 4096);          // 4*32*1024 f = 512 KB
    size_t off = (size_t)1 << 20;
    u16* WqkvT = (u16*)(base + off); off += (size_t)8 * 3072 * 1024 * 2;
    u16* WoT   = (u16*)(base + off); off += (size_t)8 * 1024 * 1024 * 2;
    u16* WguT  = (u16*)(base + off); off += (size_t)8 * 1536 * 1024 * 2;
    u16* WdT   = (u16*)(base + off); off += (size_t)8 * 1024 * 768 * 2;
    u16* hb    = (u16*)(base + off); off += (size_t)4 * 1024 * 1024 * 2;
    u16* qkvb  = (u16*)(base + off); off += (size_t)8 * 1024 * 3072 * 2;
    u16* Qb    = (u16*)(base + off); off += (size_t)8 * 1024 * 1024 * 2;
    u16* Kb    = (u16*)(base + off); off += (size_t)8 * 1024 * 1024 * 2;
    u16* Vtg   = (u16*)(base + off); off += (size_t)8 * 1024 * 1024 * 2;
    u16* ctxb  = (u16*)(base + off); off += (size_t)8 * 1024 * 1024 * 2;
    float* R1  = (float*)(base + off); off += (size_t)8 * 1024 * 1024 * 4;
    u16* xnb   = (u16*)(base + off); off += (size_t)8 * 1024 * 1024 * 2;
    u16* gub   = qkvb;                                 // overlay: qkvb dead after rope/vtrans
    u16* actb  = qkvb + (size_t)8 * 1024 * 1536;

    route1<<<dim3(4, 32), 256, 0, stream>>>(hidden, routeP);
    route2<<<4, 256, 0, stream>>>(routeP, Wr, temp, out_logits, flat_idx, flat_w);
    cast_hidden<<<4096, 256, 0, stream>>>(hidden, hb);
    wtrans<<<dim3(48, 16, 8), 256, 0, stream>>>(Wqkv, WqkvT, 1024, 3072);
    wtrans<<<dim3(16, 16, 8), 256, 0, stream>>>(Wo, WoT, 1024, 1024);
    wtrans<<<dim3(24, 16, 8), 256, 0, stream>>>(Wgu, WguT, 1024, 1536);
    wtrans<<<dim3(16, 12, 8), 256, 0, stream>>>(Wd, WdT, 768, 1024);

    gemm_bf16<1><<<dim3(24, 8, 8), 256, 0, stream>>>(hb, WqkvT, qkvb, flat_idx, 1024, 3072, 1024, 2);
    rope_cast<<<2048, 256, 0, stream>>>(qkvb, cosb, sinb, Qb, Kb);
    vtrans<<<dim3(16, 128), 256, 0, stream>>>(qkvb, Vtg);
    attn_mfma<<<dim3(8, 16, 16), 256, 0, stream>>>(Qb, Kb, Vtg, ctxb);
    gemm_bf16<0><<<dim3(8, 8, 8), 256, 0, stream>>>(ctxb, WoT, R1, flat_idx, 1024, 1024, 1024, 1);
    add_rmsnorm<<<NE_ * SEQ_, 256, 0, stream>>>(hidden, R1, xnb);
    gemm_bf16<1><<<dim3(12, 8, 8), 256, 0, stream>>>(xnb, WguT, gub, flat_idx, 1024, 1536, 1024, 1);
    silu_mul<<<3072, 256, 0, stream>>>(gub, actb);
    gemm_bf16<0><<<dim3(8, 8, 8), 256, 0, stream>>>(actb, WdT, R1, flat_idx, 1024, 1024, 768, 1);
    final_kernel<<<B_ * SEQ_, 256, 0, stream>>>(xnb, R1, flat_w, out);
}

// Round 4
// 573.202 us; speedup vs baseline: 5.3929x; 1.0312x over previous
//
#include <hip/hip_runtime.h>
#include <hip/hip_bf16.h>
#include <math.h>

#define B_     4
#define SEQ_   1024
#define D_     1024
#define H_     16
#define NE_    8
#define INTER_ 768
#define EPS_   1e-5f

typedef unsigned short u16;
typedef __attribute__((ext_vector_type(8))) short s8v;      // 8 bf16 (4 VGPRs) - MFMA A/B frag (x32)
typedef __attribute__((ext_vector_type(4))) short s4v;      // 4 bf16 (2 VGPRs) - MFMA A/B frag (x16)
typedef __attribute__((ext_vector_type(4))) float f4v;      // MFMA C/D frag
typedef __attribute__((ext_vector_type(4))) unsigned short u16x4;
typedef __attribute__((ext_vector_type(8))) unsigned short u16x8;

__device__ __forceinline__ u16 f2bf(float x) {
    union { float f; unsigned u; } c; c.f = x;
    unsigned r = (c.u + 0x7FFFu + ((c.u >> 16) & 1u)) >> 16;
    return (u16)r;
}
__device__ __forceinline__ float bf2f(u16 h) {
    union { unsigned u; float f; } c; c.u = ((unsigned)h) << 16;
    return c.f;
}
__device__ __forceinline__ unsigned pk2(float a, float b) {
    union { float f; unsigned u; } x, y; x.f = a; y.f = b;
    return ((x.u + 0x8000u) >> 16) | ((y.u + 0x8000u) & 0xffff0000u);
}

#define GLDS16(gp, lp) \
    __builtin_amdgcn_global_load_lds((const __attribute__((address_space(1))) unsigned int*)(gp), \
                                     (__attribute__((address_space(3))) unsigned int*)(lp), 16, 0, 0)

// ---------------- routing, 2-stage ----------------
__global__ void route1(const float* __restrict__ hidden, float* __restrict__ part) {
    int b = blockIdx.x, ch = blockIdx.y, t = threadIdx.x;
    const float* xb = hidden + (size_t)b * SEQ_ * D_ + (size_t)ch * 32 * D_;
    float4 acc = make_float4(0.f, 0.f, 0.f, 0.f);
    for (int r = 0; r < 32; ++r) {
        float4 v = *(const float4*)&xb[(size_t)r * D_ + t * 4];
        acc.x += v.x; acc.y += v.y; acc.z += v.z; acc.w += v.w;
    }
    *(float4*)&part[((size_t)(b * 32 + ch)) * D_ + t * 4] = acc;
}

__global__ void route2(const float* __restrict__ part, const float* __restrict__ Wr,
                       const float* __restrict__ temp, float* __restrict__ out_logits,
                       int* __restrict__ flat_idx, float* __restrict__ flat_w) {
    __shared__ float col[1024];
    __shared__ float sm[8];
    int b = blockIdx.x, t = threadIdx.x;
    float4 s = make_float4(0.f, 0.f, 0.f, 0.f);
    for (int ch = 0; ch < 32; ++ch) {
        float4 v = *(const float4*)&part[((size_t)(b * 32 + ch)) * D_ + t * 4];
        s.x += v.x; s.y += v.y; s.z += v.z; s.w += v.w;
    }
    col[t * 4 + 0] = s.x * (1.f / 1024.f);
    col[t * 4 + 1] = s.y * (1.f / 1024.f);
    col[t * 4 + 2] = s.z * (1.f / 1024.f);
    col[t * 4 + 3] = s.w * (1.f / 1024.f);
    __syncthreads();
    int j = t >> 5, d0 = t & 31;
    float p = 0.f;
    for (int d = d0; d < 1024; d += 32) p += col[d] * Wr[j * 1024 + d];
    for (int off = 16; off >= 1; off >>= 1) p += __shfl_down(p, off, 32);
    if (d0 == 0) sm[j] = p;
    __syncthreads();
    if (t == 0) {
        float tc = temp[0];
        tc = fminf(fmaxf(tc, 0.1f), 10.0f);
        float lg[8];
        for (int jj = 0; jj < 8; ++jj) {
            lg[jj] = sm[jj] / tc;
            out_logits[b * 8 + jj] = lg[jj];
        }
        int i0 = 0; float v0 = lg[0];
        for (int jj = 1; jj < 8; ++jj) if (lg[jj] > v0) { v0 = lg[jj]; i0 = jj; }
        int i1 = -1; float v1 = -1e30f;
        for (int jj = 0; jj < 8; ++jj) if (jj != i0 && lg[jj] > v1) { v1 = lg[jj]; i1 = jj; }
        float e1 = expf(v1 - v0);
        flat_idx[2 * b]     = i0;
        flat_idx[2 * b + 1] = i1;
        flat_w[2 * b]       = 1.0f / (1.0f + e1);
        flat_w[2 * b + 1]   = e1 / (1.0f + e1);
    }
}

// ---------------- weight transpose+cast ----------------
__global__ __launch_bounds__(256) void wtrans(const float* __restrict__ W, u16* __restrict__ Wt,
                                              int K, int N) {
    __shared__ float tile[64][65];
    int e = blockIdx.z;
    int k0 = blockIdx.y * 64, n0 = blockIdx.x * 64;
    const float* Wp = W + (size_t)e * K * N;
    u16* Wtp = Wt + (size_t)e * K * N;
    int t = threadIdx.x;
    int kk = t >> 4, ns = t & 15;
#pragma unroll
    for (int p = 0; p < 4; ++p) {
        float4 v = *(const float4*)&Wp[(size_t)(k0 + kk + p * 16) * N + n0 + ns * 4];
        tile[kk + p * 16][ns * 4 + 0] = v.x;
        tile[kk + p * 16][ns * 4 + 1] = v.y;
        tile[kk + p * 16][ns * 4 + 2] = v.z;
        tile[kk + p * 16][ns * 4 + 3] = v.w;
    }
    __syncthreads();
    int nn = t >> 3, ks = t & 7;
#pragma unroll
    for (int p = 0; p < 2; ++p) {
        u16x8 o;
#pragma unroll
        for (int jj = 0; jj < 8; ++jj) o[jj] = f2bf(tile[ks * 8 + jj][nn + p * 32]);
        *(u16x8*)&Wtp[(size_t)(n0 + nn + p * 32) * K + k0 + ks * 8] = o;
    }
}

// ---------------- cast hidden f32 -> bf16 ----------------
__global__ void cast_hidden(const float* __restrict__ x, u16* __restrict__ xb) {
    size_t i = (size_t)blockIdx.x * 256 + threadIdx.x;
    float4 v = *(const float4*)&x[i * 4];
    u16x4 o = {f2bf(v.x), f2bf(v.y), f2bf(v.z), f2bf(v.w)};
    *(u16x4*)&xb[i * 4] = o;
}

// K-loop core (shared by gemm kernels). Produces acc[4][4] f4v.
// LDS seg swizzle: stored seg ss of row r holds data seg ss^((r>>1)&3).
#define GEMM_CORE(A, Wt, K)                                                                 \
    f4v acc[4][4];                                                                          \
    _Pragma("unroll") for (int i = 0; i < 4; ++i)                                           \
        _Pragma("unroll") for (int jj = 0; jj < 4; ++jj) acc[i][jj] = (f4v){0.f,0.f,0.f,0.f}; \
    for (int k0 = 0; k0 < K; k0 += 32) {                                                    \
        _Pragma("unroll") for (int it = 0; it < 2; ++it) {                                  \
            int p = it * 256 + w * 64 + lane;                                               \
            int row = p >> 2, seg = (p & 3) ^ ((row >> 1) & 3);                             \
            GLDS16(A  + (size_t)(m0 + row) * K + k0 + seg * 8, As + (size_t)(it*256 + w*64) * 8); \
            GLDS16(Wt + (size_t)(n0 + row) * K + k0 + seg * 8, Bs + (size_t)(it*256 + w*64) * 8); \
        }                                                                                   \
        __syncthreads();                                                                    \
        s8v af[4], bfr[4];                                                                  \
        _Pragma("unroll") for (int ti = 0; ti < 4; ++ti) {                                  \
            int r = wm + ti * 16 + c;                                                       \
            af[ti]  = *(const s8v*)&As[r * 32 + (g ^ ((r >> 1) & 3)) * 8];                   \
        }                                                                                   \
        _Pragma("unroll") for (int tj = 0; tj < 4; ++tj) {                                  \
            int r = wn + tj * 16 + c;                                                       \
            bfr[tj] = *(const s8v*)&Bs[r * 32 + (g ^ ((r >> 1) & 3)) * 8];                   \
        }                                                                                   \
        _Pragma("unroll") for (int ti = 0; ti < 4; ++ti)                                    \
            _Pragma("unroll") for (int tj = 0; tj < 4; ++tj)                                \
                acc[ti][tj] = __builtin_amdgcn_mfma_f32_16x16x32_bf16(af[ti], bfr[tj], acc[ti][tj], 0, 0, 0); \
        __syncthreads();                                                                    \
    }

// ---------------- generic bf16 MFMA GEMM ----------------
template<int OUTBF>
__global__ __launch_bounds__(256) void gemm_bf16(const u16* __restrict__ Abase,
                                                 const u16* __restrict__ Wtbase,
                                                 void* __restrict__ Cb,
                                                 const int* __restrict__ flat_idx,
                                                 int M, int N, int K, int aDiv) {
    __shared__ __align__(16) u16 As[128 * 32];
    __shared__ __align__(16) u16 Bs[128 * 32];
    int e = blockIdx.z;
    const u16* A  = Abase + (size_t)(e / aDiv) * M * K;
    const u16* Wt = Wtbase + (size_t)flat_idx[e] * N * K;
    int m0 = blockIdx.y * 128, n0 = blockIdx.x * 128;
    int t = threadIdx.x, lane = t & 63, w = t >> 6;
    int g = lane >> 4, c = lane & 15;
    int wm = (w >> 1) * 64, wn = (w & 1) * 64;

    GEMM_CORE(A, Wt, K)

    if (OUTBF) {
        u16* C = (u16*)Cb + (size_t)e * M * N;
#pragma unroll
        for (int ti = 0; ti < 4; ++ti)
#pragma unroll
            for (int tj = 0; tj < 4; ++tj)
#pragma unroll
                for (int i = 0; i < 4; ++i)
                    C[(size_t)(m0 + wm + ti * 16 + g * 4 + i) * N + n0 + wn + tj * 16 + c] = f2bf(acc[ti][tj][i]);
    } else {
        float* C = (float*)Cb + (size_t)e * M * N;
#pragma unroll
        for (int ti = 0; ti < 4; ++ti)
#pragma unroll
            for (int tj = 0; tj < 4; ++tj)
#pragma unroll
                for (int i = 0; i < 4; ++i)
                    C[(size_t)(m0 + wm + ti * 16 + g * 4 + i) * N + n0 + wn + tj * 16 + c] = acc[ti][tj][i];
    }
}

// ---------------- qkv GEMM with fused RoPE/scale/split epilogue ----------------
// N=3072. x<8: Q (RoPE + 0.125*log2e scale), x<16: K (RoPE), else: V straight.
__global__ __launch_bounds__(256) void gemm_qkv(const u16* __restrict__ Abase,
                                                const u16* __restrict__ Wtbase,
                                                const int* __restrict__ flat_idx,
                                                const float* __restrict__ cosb,
                                                const float* __restrict__ sinb,
                                                u16* __restrict__ Qb, u16* __restrict__ Kb,
                                                u16* __restrict__ Vb) {
    __shared__ __align__(16) u16 As[128 * 32];
    __shared__ __align__(16) u16 Bs[128 * 32];
    const int K = 1024, N = 3072;
    int e = blockIdx.z;
    const u16* A  = Abase + (size_t)(e >> 1) * 1024 * K;
    const u16* Wt = Wtbase + (size_t)flat_idx[e] * N * K;
    int m0 = blockIdx.y * 128, n0 = blockIdx.x * 128;
    int t = threadIdx.x, lane = t & 63, w = t >> 6;
    int g = lane >> 4, c = lane & 15;
    int wm = (w >> 1) * 64, wn = (w & 1) * 64;

    GEMM_CORE(A, Wt, K)

    int col0 = n0 + wn;                 // multiple of 64
    int sb = m0 + wm + g * 4;
    if (col0 < 2048) {
        bool isq = col0 < 1024;
        u16* dst = isq ? Qb : Kb;
        int h = (col0 & 1023) >> 6;
        const float scl = isq ? 0.125f * 1.44269504f : 1.0f;
#pragma unroll
        for (int ti = 0; ti < 4; ++ti)
#pragma unroll
            for (int i = 0; i < 4; ++i) {
                int s = sb + ti * 16 + i;
                size_t ob = ((size_t)(e * 1024) + s) * 1024 + h * 64;
#pragma unroll
                for (int tj = 0; tj < 2; ++tj) {
                    int d = tj * 16 + c;
                    float x1 = acc[ti][tj][i], x2 = acc[ti][tj + 2][i];
                    float c1 = cosb[s * 64 + d],      s1 = sinb[s * 64 + d];
                    float c2 = cosb[s * 64 + d + 32], s2 = sinb[s * 64 + d + 32];
                    dst[ob + d]      = f2bf((x1 * c1 - x2 * s1) * scl);
                    dst[ob + d + 32] = f2bf((x2 * c2 + x1 * s2) * scl);
                }
            }
    } else {
        int vcol = col0 - 2048;
#pragma unroll
        for (int ti = 0; ti < 4; ++ti)
#pragma unroll
            for (int tj = 0; tj < 4; ++tj)
#pragma unroll
                for (int i = 0; i < 4; ++i)
                    Vb[((size_t)(e * 1024) + sb + ti * 16 + i) * 1024 + vcol + tj * 16 + c] = f2bf(acc[ti][tj][i]);
    }
}

// ---------------- V transpose: Vb[e][s][d] -> Vtg[e][h][d=64][kv=1024] ----------------
__global__ __launch_bounds__(256) void vtrans(const u16* __restrict__ Vb, u16* __restrict__ Vtg) {
    __shared__ __align__(16) u16 tile[64 * 72];
    int s0 = blockIdx.x * 64;
    int eh = blockIdx.y;
    int e = eh >> 4, h = eh & 15;
    int t = threadIdx.x;
#pragma unroll
    for (int it = 0; it < 2; ++it) {
        int p = it * 256 + t;
        int sr = p >> 3, ds = p & 7;
        u16x8 v = *(const u16x8*)&Vb[((size_t)(e * 1024) + s0 + sr) * 1024 + h * 64 + ds * 8];
        *(u16x8*)&tile[sr * 72 + ds * 8] = v;
    }
    __syncthreads();
#pragma unroll
    for (int it = 0; it < 2; ++it) {
        int p = it * 256 + t;
        int d = p >> 3, ks = p & 7;
        u16x8 o;
#pragma unroll
        for (int jj = 0; jj < 8; ++jj) o[jj] = tile[(ks * 8 + jj) * 72 + d];
        *(u16x8*)&Vtg[((size_t)((e * 16 + h) * 64) + d) * 1024 + s0 + ks * 8] = o;
    }
}

// ---------------- MFMA flash attention (S^T = K Q^T; register P) ----------------
__global__ __launch_bounds__(256) void attn_mfma(const u16* __restrict__ Qb, const u16* __restrict__ Kb,
                                                 const u16* __restrict__ Vtg, u16* __restrict__ ctx) {
    __shared__ __align__(16) u16 Ks[64 * 64];
    __shared__ __align__(16) u16 Vt[64 * 64];
    int e = blockIdx.x, h = blockIdx.y, qt = blockIdx.z;
    int t = threadIdx.x, lane = t & 63, w = t >> 6;
    int g = lane >> 4, c = lane & 15;
    int q0 = qt * 64 + w * 16;

    s8v qf[2];
#pragma unroll
    for (int ks = 0; ks < 2; ++ks)
        qf[ks] = *(const s8v*)&Qb[((size_t)(e * 1024) + q0 + c) * 1024 + h * 64 + ks * 32 + g * 8];

    f4v O[4];
#pragma unroll
    for (int tj = 0; tj < 4; ++tj) O[tj] = (f4v){0.f, 0.f, 0.f, 0.f};
    f4v liacc = (f4v){0.f, 0.f, 0.f, 0.f};
    const s4v vone = {(short)0x3F80, (short)0x3F80, (short)0x3F80, (short)0x3F80};

    for (int kt = 0; kt < 16; ++kt) {
#pragma unroll
        for (int it = 0; it < 2; ++it) {
            int p = it * 256 + w * 64 + lane;
            int row = p >> 3, ss = p & 7;
            GLDS16(Kb + ((size_t)(e * 1024 + kt * 64 + row)) * 1024 + h * 64 + (ss ^ (row & 7)) * 8,
                   Ks + (size_t)(it * 256 + w * 64) * 8);
            GLDS16(Vtg + ((size_t)((e * 16 + h) * 64 + row)) * 1024 + kt * 64 + (ss ^ (row & 7)) * 8,
                   Vt + (size_t)(it * 256 + w * 64) * 8);
        }
        __syncthreads();

        f4v st[4];
#pragma unroll
        for (int tj = 0; tj < 4; ++tj) st[tj] = (f4v){0.f, 0.f, 0.f, 0.f};
#pragma unroll
        for (int ks = 0; ks < 2; ++ks)
#pragma unroll
            for (int tj = 0; tj < 4; ++tj) {
                int kvl = tj * 16 + c;
                s8v kf = *(const s8v*)&Ks[kvl * 64 + (((ks * 4 + g) ^ (kvl & 7)) * 8)];
                st[tj] = __builtin_amdgcn_mfma_f32_16x16x32_bf16(kf, qf[ks], st[tj], 0, 0, 0);
            }

        s4v pf[4];
#pragma unroll
        for (int tj = 0; tj < 4; ++tj) {
            float p0 = __builtin_amdgcn_exp2f(st[tj][0]);
            float p1 = __builtin_amdgcn_exp2f(st[tj][1]);
            float p2 = __builtin_amdgcn_exp2f(st[tj][2]);
            float p3 = __builtin_amdgcn_exp2f(st[tj][3]);
            union { unsigned u[2]; s4v v; } pu;
            pu.u[0] = pk2(p0, p1);
            pu.u[1] = pk2(p2, p3);
            pf[tj] = pu.v;
        }

#pragma unroll
        for (int tjC = 0; tjC < 4; ++tjC) {
            liacc = __builtin_amdgcn_mfma_f32_16x16x16bf16_1k(pf[tjC], vone, liacc, 0, 0, 0);
#pragma unroll
            for (int tjd = 0; tjd < 4; ++tjd) {
                int d = tjd * 16 + c;
                int sd = tjC * 2 + (g >> 1);
                s4v vf = *(const s4v*)&Vt[d * 64 + ((sd ^ (d & 7)) * 8) + (g & 1) * 4];
                O[tjd] = __builtin_amdgcn_mfma_f32_16x16x16bf16_1k(pf[tjC], vf, O[tjd], 0, 0, 0);
            }
        }
        __syncthreads();
    }
#pragma unroll
    for (int i = 0; i < 4; ++i) {
        float linv = 1.0f / liacc[i];
        size_t rbase = ((size_t)(e * 1024) + q0 + g * 4 + i) * 1024 + h * 64;
#pragma unroll
        for (int tjd = 0; tjd < 4; ++tjd)
            ctx[rbase + tjd * 16 + c] = f2bf(O[tjd][i] * linv);
    }
}

// ---------------- xnb = bf16(rmsnorm(hidden[b] + attn_out)) ----------------
__global__ void add_rmsnorm(const float* __restrict__ hidden, const float* __restrict__ ao,
                            u16* __restrict__ xnb) {
    int row = blockIdx.x;
    int e = row >> 10;
    int b = e >> 1;
    int s = row & 1023;
    const float* xr = hidden + (((size_t)b * SEQ_ + s) << 10);
    const float* ar = ao + ((size_t)row << 10);
    u16* o = xnb + ((size_t)row << 10);
    int t = threadIdx.x;
    float v[4];
    float ss = 0.f;
#pragma unroll
    for (int i = 0; i < 4; ++i) {
        v[i] = xr[t + i * 256] + ar[t + i * 256];
        ss += v[i] * v[i];
    }
    for (int off = 32; off >= 1; off >>= 1) ss += __shfl_down(ss, off, 64);
    __shared__ float wred[4];
    if ((t & 63) == 0) wred[t >> 6] = ss;
    __syncthreads();
    float tot = wred[0] + wred[1] + wred[2] + wred[3];
    float scale = rsqrtf(tot * (1.0f / 1024.0f) + EPS_);
#pragma unroll
    for (int i = 0; i < 4; ++i) o[t + i * 256] = f2bf(v[i] * scale);
}

// ---------------- act = silu(gate) * up ----------------
__global__ void silu_mul(const u16* __restrict__ gub, u16* __restrict__ act) {
    int idx = blockIdx.x * 256 + threadIdx.x;
    int col8 = idx % 96;
    int row  = idx / 96;
    u16x8 gv = *(const u16x8*)&gub[(size_t)row * 1536 + col8 * 8];
    u16x8 uv = *(const u16x8*)&gub[(size_t)row * 1536 + 768 + col8 * 8];
    u16x8 o;
#pragma unroll
    for (int jj = 0; jj < 8; ++jj) {
        float gt = bf2f(gv[jj]), u = bf2f(uv[jj]);
        o[jj] = f2bf(gt / (1.f + __expf(-gt)) * u);
    }
    *(u16x8*)&act[(size_t)row * 768 + col8 * 8] = o;
}

// ---------------- out[b] = sum_j w_e * rmsnorm(xn[e] + mlp[e]) ----------------
__global__ void final_kernel(const u16* __restrict__ xnb, const float* __restrict__ mlp,
                             const float* __restrict__ flat_w, float* __restrict__ out) {
    int row = blockIdx.x;
    int b = row >> 10;
    int s = row & 1023;
    int t = threadIdx.x;
    __shared__ float wred[4];
    float res[4] = {0.f, 0.f, 0.f, 0.f};
    for (int j = 0; j < 2; ++j) {
        int e = 2 * b + j;
        size_t off = (((size_t)e * SEQ_ + s) << 10);
        const u16* xr = xnb + off;
        const float* mr = mlp + off;
        float v[4];
        float ss = 0.f;
#pragma unroll
        for (int i = 0; i < 4; ++i) {
            v[i] = bf2f(xr[t + i * 256]) + mr[t + i * 256];
            ss += v[i] * v[i];
        }
        for (int off2 = 32; off2 >= 1; off2 >>= 1) ss += __shfl_down(ss, off2, 64);
        if ((t & 63) == 0) wred[t >> 6] = ss;
        __syncthreads();
        float tot = wred[0] + wred[1] + wred[2] + wred[3];
        float scale = rsqrtf(tot * (1.0f / 1024.0f) + EPS_);
        float wgt = flat_w[e];
#pragma unroll
        for (int i = 0; i < 4; ++i) res[i] += wgt * v[i] * scale;
        __syncthreads();
    }
    float* o = out + ((size_t)row << 10);
#pragma unroll
    for (int i = 0; i < 4; ++i) o[t + i * 256] = res[i];
}

extern "C" void kernel_launch(void* const* d_in, const int* in_sizes, int n_in,
                              void* d_out, int out_size, void* d_ws, size_t ws_size,
                              hipStream_t stream) {
    const float* hidden = (const float*)d_in[0];
    const float* cosb   = (const float*)d_in[1];
    const float* sinb   = (const float*)d_in[2];
    const float* Wr     = (const float*)d_in[3];
    const float* temp   = (const float*)d_in[4];
    const float* Wqkv   = (const float*)d_in[5];
    const float* Wo     = (const float*)d_in[6];
    const float* Wgu    = (const float*)d_in[7];
    const float* Wd     = (const float*)d_in[8];
    float* out = (float*)d_out;
    float* out_logits = out + (size_t)B_ * SEQ_ * D_;

    char* base = (char*)d_ws;
    int*   flat_idx = (int*)base;
    float* flat_w   = (float*)(base + 128);
    float* routeP   = (float*)(base + 4096);
    size_t off = (size_t)1 << 20;
    u16* WqkvT = (u16*)(base + off); off += (size_t)8 * 3072 * 1024 * 2;
    u16* WoT   = (u16*)(base + off); off += (size_t)8 * 1024 * 1024 * 2;
    u16* WguT  = (u16*)(base + off); off += (size_t)8 * 1536 * 1024 * 2;
    u16* WdT   = (u16*)(base + off); off += (size_t)8 * 1024 * 768 * 2;
    u16* hb    = (u16*)(base + off); off += (size_t)4 * 1024 * 1024 * 2;
    u16* scr   = (u16*)(base + off); off += (size_t)8 * 1024 * 3072 * 2;  // gub/actb overlay
    u16* Qb    = (u16*)(base + off); off += (size_t)8 * 1024 * 1024 * 2;
    u16* Kb    = (u16*)(base + off); off += (size_t)8 * 1024 * 1024 * 2;
    u16* Vtg   = (u16*)(base + off); off += (size_t)8 * 1024 * 1024 * 2;
    u16* ctxb  = (u16*)(base + off); off += (size_t)8 * 1024 * 1024 * 2;
    float* R1  = (float*)(base + off); off += (size_t)8 * 1024 * 1024 * 4;
    u16* xnb   = (u16*)(base + off); off += (size_t)8 * 1024 * 1024 * 2;
    u16* gub   = scr;
    u16* actb  = scr + (size_t)8 * 1024 * 1536;
    u16* Vb    = (u16*)R1;   // alias: Vb dead before wo-GEMM writes R1

    route1<<<dim3(4, 32), 256, 0, stream>>>(hidden, routeP);
    route2<<<4, 256, 0, stream>>>(routeP, Wr, temp, out_logits, flat_idx, flat_w);
    cast_hidden<<<4096, 256, 0, stream>>>(hidden, hb);
    wtrans<<<dim3(48, 16, 8), 256, 0, stream>>>(Wqkv, WqkvT, 1024, 3072);
    wtrans<<<dim3(16, 16, 8), 256, 0, stream>>>(Wo, WoT, 1024, 1024);
    wtrans<<<dim3(24, 16, 8), 256, 0, stream>>>(Wgu, WguT, 1024, 1536);
    wtrans<<<dim3(16, 12, 8), 256, 0, stream>>>(Wd, WdT, 768, 1024);

    gemm_qkv<<<dim3(24, 8, 8), 256, 0, stream>>>(hb, WqkvT, flat_idx, cosb, sinb, Qb, Kb, Vb);
    vtrans<<<dim3(16, 128), 256, 0, stream>>>(Vb, Vtg);
    attn_mfma<<<dim3(8, 16, 16), 256, 0, stream>>>(Qb, Kb, Vtg, ctxb);
    gemm_bf16<0><<<dim3(8, 8, 8), 256, 0, stream>>>(ctxb, WoT, R1, flat_idx, 1024, 1024, 1024, 1);
    add_rmsnorm<<<NE_ * SEQ_, 256, 0, stream>>>(hidden, R1, xnb);
    gemm_bf16<1><<<dim3(12, 8, 8), 256, 0, stream>>>(xnb, WguT, gub, flat_idx, 1024, 1536, 1024, 1);
    silu_mul<<<3072, 256, 0, stream>>>(gub, actb);
    gemm_bf16<0><<<dim3(8, 8, 8), 256, 0, stream>>>(actb, WdT, R1, flat_idx, 1024, 1024, 768, 1);
    final_kernel<<<B_ * SEQ_, 256, 0, stream>>>(xnb, R1, flat_w, out);
}

// Round 5
// 546.845 us; speedup vs baseline: 5.6528x; 1.0482x over previous
//
#include <hip/hip_runtime.h>
#include <hip/hip_bf16.h>
#include <math.h>

#define B_     4
#define SEQ_   1024
#define D_     1024
#define H_     16
#define NE_    8
#define INTER_ 768
#define EPS_   1e-5f

typedef unsigned short u16;
typedef __attribute__((ext_vector_type(8))) short s8v;      // 8 bf16 - MFMA A/B frag (K=32)
typedef __attribute__((ext_vector_type(4))) short s4v;      // 4 bf16 - MFMA A/B frag (K=16)
typedef __attribute__((ext_vector_type(4))) float f4v;      // MFMA C/D frag
typedef __attribute__((ext_vector_type(4))) unsigned short u16x4;
typedef __attribute__((ext_vector_type(8))) unsigned short u16x8;

__device__ __forceinline__ u16 f2bf(float x) {
    union { float f; unsigned u; } c; c.f = x;
    unsigned r = (c.u + 0x7FFFu + ((c.u >> 16) & 1u)) >> 16;
    return (u16)r;
}
__device__ __forceinline__ float bf2f(u16 h) {
    union { unsigned u; float f; } c; c.u = ((unsigned)h) << 16;
    return c.f;
}
__device__ __forceinline__ unsigned pk2(float a, float b) {
    union { float f; unsigned u; } x, y; x.f = a; y.f = b;
    return ((x.u + 0x8000u) >> 16) | ((y.u + 0x8000u) & 0xffff0000u);
}

#define GLDS16(gp, lp) \
    __builtin_amdgcn_global_load_lds((const __attribute__((address_space(1))) unsigned int*)(gp), \
                                     (__attribute__((address_space(3))) unsigned int*)(lp), 16, 0, 0)

// ---------------- routing stage 1 + bf16 cast of hidden ----------------
__global__ void route1(const float* __restrict__ hidden, float* __restrict__ part,
                       u16* __restrict__ hb) {
    int b = blockIdx.x, ch = blockIdx.y, t = threadIdx.x;
    const float* xb = hidden + (size_t)b * SEQ_ * D_ + (size_t)ch * 32 * D_;
    u16* ho = hb + (size_t)b * SEQ_ * D_ + (size_t)ch * 32 * D_;
    float4 acc = make_float4(0.f, 0.f, 0.f, 0.f);
    for (int r = 0; r < 32; ++r) {
        float4 v = *(const float4*)&xb[(size_t)r * D_ + t * 4];
        acc.x += v.x; acc.y += v.y; acc.z += v.z; acc.w += v.w;
        u16x4 o = {f2bf(v.x), f2bf(v.y), f2bf(v.z), f2bf(v.w)};
        *(u16x4*)&ho[(size_t)r * D_ + t * 4] = o;
    }
    *(float4*)&part[((size_t)(b * 32 + ch)) * D_ + t * 4] = acc;
}

__global__ void route2(const float* __restrict__ part, const float* __restrict__ Wr,
                       const float* __restrict__ temp, float* __restrict__ out_logits,
                       int* __restrict__ flat_idx, float* __restrict__ flat_w) {
    __shared__ float col[1024];
    __shared__ float sm[8];
    int b = blockIdx.x, t = threadIdx.x;
    float4 s = make_float4(0.f, 0.f, 0.f, 0.f);
    for (int ch = 0; ch < 32; ++ch) {
        float4 v = *(const float4*)&part[((size_t)(b * 32 + ch)) * D_ + t * 4];
        s.x += v.x; s.y += v.y; s.z += v.z; s.w += v.w;
    }
    col[t * 4 + 0] = s.x * (1.f / 1024.f);
    col[t * 4 + 1] = s.y * (1.f / 1024.f);
    col[t * 4 + 2] = s.z * (1.f / 1024.f);
    col[t * 4 + 3] = s.w * (1.f / 1024.f);
    __syncthreads();
    int j = t >> 5, d0 = t & 31;
    float p = 0.f;
    for (int d = d0; d < 1024; d += 32) p += col[d] * Wr[j * 1024 + d];
    for (int off = 16; off >= 1; off >>= 1) p += __shfl_down(p, off, 32);
    if (d0 == 0) sm[j] = p;
    __syncthreads();
    if (t == 0) {
        float tc = temp[0];
        tc = fminf(fmaxf(tc, 0.1f), 10.0f);
        float lg[8];
        for (int jj = 0; jj < 8; ++jj) {
            lg[jj] = sm[jj] / tc;
            out_logits[b * 8 + jj] = lg[jj];
        }
        int i0 = 0; float v0 = lg[0];
        for (int jj = 1; jj < 8; ++jj) if (lg[jj] > v0) { v0 = lg[jj]; i0 = jj; }
        int i1 = -1; float v1 = -1e30f;
        for (int jj = 0; jj < 8; ++jj) if (jj != i0 && lg[jj] > v1) { v1 = lg[jj]; i1 = jj; }
        float e1 = expf(v1 - v0);
        flat_idx[2 * b]     = i0;
        flat_idx[2 * b + 1] = i1;
        flat_w[2 * b]       = 1.0f / (1.0f + e1);
        flat_w[2 * b + 1]   = e1 / (1.0f + e1);
    }
}

// ---------------- combined weight transpose+cast (all 4 weights, one dispatch) ----------------
// ranges: [0,6144) Wqkv (K1024,N3072) | [6144,8192) Wo (1024,1024)
//         [8192,11264) Wgu (1024,1536, gate/up interleave perm) | [11264,12800) Wd (768,1024)
__global__ __launch_bounds__(256) void wtrans_all(const float* __restrict__ Wqkv,
                                                  const float* __restrict__ Wo,
                                                  const float* __restrict__ Wgu,
                                                  const float* __restrict__ Wd,
                                                  u16* __restrict__ WqkvT, u16* __restrict__ WoT,
                                                  u16* __restrict__ WguT, u16* __restrict__ WdT) {
    int bid = blockIdx.x;
    const float* W; u16* Wt; int K, N, nx, gu = 0;
    if (bid < 6144)      { W = Wqkv; Wt = WqkvT; K = 1024; N = 3072; nx = 48; }
    else if (bid < 8192) { bid -= 6144;  W = Wo;  Wt = WoT;  K = 1024; N = 1024; nx = 16; }
    else if (bid < 11264){ bid -= 8192;  W = Wgu; Wt = WguT; K = 1024; N = 1536; nx = 24; gu = 1; }
    else                 { bid -= 11264; W = Wd;  Wt = WdT;  K = 768;  N = 1024; nx = 16; }
    int x = bid % nx; bid /= nx;
    int ny = K >> 6;
    int y = bid % ny;
    int e = bid / ny;

    __shared__ float tile[64][65];
    int k0 = y * 64, n0 = x * 64;
    const float* Wp = W + (size_t)e * K * N;
    u16* Wtp = Wt + (size_t)e * K * N;
    int t = threadIdx.x;
    int kk = t >> 4, ns = t & 15;
#pragma unroll
    for (int p = 0; p < 4; ++p) {
        float4 v = *(const float4*)&Wp[(size_t)(k0 + kk + p * 16) * N + n0 + ns * 4];
        tile[kk + p * 16][ns * 4 + 0] = v.x;
        tile[kk + p * 16][ns * 4 + 1] = v.y;
        tile[kk + p * 16][ns * 4 + 2] = v.z;
        tile[kk + p * 16][ns * 4 + 3] = v.w;
    }
    __syncthreads();
    int nn = t >> 3, ks = t & 7;
#pragma unroll
    for (int p = 0; p < 2; ++p) {
        int n = n0 + nn + p * 32;
        int nd = n;
        if (gu) nd = (n < 768) ? ((n >> 4) << 5) + (n & 15)
                               : (((n - 768) >> 4) << 5) + 16 + (n & 15);
        u16x8 o;
#pragma unroll
        for (int jj = 0; jj < 8; ++jj) o[jj] = f2bf(tile[ks * 8 + jj][nn + p * 32]);
        *(u16x8*)&Wtp[(size_t)nd * K + k0 + ks * 8] = o;
    }
}

// K-loop core. LDS seg swizzle: stored seg ss of row r holds data seg ss^((r>>1)&3).
#define GEMM_CORE(A, Wt, K)                                                                 \
    f4v acc[4][4];                                                                          \
    _Pragma("unroll") for (int i = 0; i < 4; ++i)                                           \
        _Pragma("unroll") for (int jj = 0; jj < 4; ++jj) acc[i][jj] = (f4v){0.f,0.f,0.f,0.f}; \
    for (int k0 = 0; k0 < K; k0 += 32) {                                                    \
        _Pragma("unroll") for (int it = 0; it < 2; ++it) {                                  \
            int p = it * 256 + w * 64 + lane;                                               \
            int row = p >> 2, seg = (p & 3) ^ ((row >> 1) & 3);                             \
            GLDS16(A  + (size_t)(m0 + row) * K + k0 + seg * 8, As + (size_t)(it*256 + w*64) * 8); \
            GLDS16(Wt + (size_t)(n0 + row) * K + k0 + seg * 8, Bs + (size_t)(it*256 + w*64) * 8); \
        }                                                                                   \
        __syncthreads();                                                                    \
        s8v af[4], bfr[4];                                                                  \
        _Pragma("unroll") for (int ti = 0; ti < 4; ++ti) {                                  \
            int r = wm + ti * 16 + c;                                                       \
            af[ti]  = *(const s8v*)&As[r * 32 + (g ^ ((r >> 1) & 3)) * 8];                   \
        }                                                                                   \
        _Pragma("unroll") for (int tj = 0; tj < 4; ++tj) {                                  \
            int r = wn + tj * 16 + c;                                                       \
            bfr[tj] = *(const s8v*)&Bs[r * 32 + (g ^ ((r >> 1) & 3)) * 8];                   \
        }                                                                                   \
        _Pragma("unroll") for (int ti = 0; ti < 4; ++ti)                                    \
            _Pragma("unroll") for (int tj = 0; tj < 4; ++tj)                                \
                acc[ti][tj] = __builtin_amdgcn_mfma_f32_16x16x32_bf16(af[ti], bfr[tj], acc[ti][tj], 0, 0, 0); \
        __syncthreads();                                                                    \
    }

// ---------------- generic bf16 MFMA GEMM (bf16 C) ----------------
__global__ __launch_bounds__(256) void gemm_bf16(const u16* __restrict__ Abase,
                                                 const u16* __restrict__ Wtbase,
                                                 u16* __restrict__ Cb,
                                                 const int* __restrict__ flat_idx,
                                                 int M, int N, int K, int aDiv) {
    __shared__ __align__(16) u16 As[128 * 32];
    __shared__ __align__(16) u16 Bs[128 * 32];
    int e = blockIdx.z;
    const u16* A  = Abase + (size_t)(e / aDiv) * M * K;
    const u16* Wt = Wtbase + (size_t)flat_idx[e] * N * K;
    int m0 = blockIdx.y * 128, n0 = blockIdx.x * 128;
    int t = threadIdx.x, lane = t & 63, w = t >> 6;
    int g = lane >> 4, c = lane & 15;
    int wm = (w >> 1) * 64, wn = (w & 1) * 64;

    GEMM_CORE(A, Wt, K)

    u16* C = Cb + (size_t)e * M * N;
#pragma unroll
    for (int ti = 0; ti < 4; ++ti)
#pragma unroll
        for (int tj = 0; tj < 4; ++tj)
#pragma unroll
            for (int i = 0; i < 4; ++i)
                C[(size_t)(m0 + wm + ti * 16 + g * 4 + i) * N + n0 + wn + tj * 16 + c] = f2bf(acc[ti][tj][i]);
}

// ---------------- qkv GEMM with fused RoPE/scale/split epilogue ----------------
__global__ __launch_bounds__(256) void gemm_qkv(const u16* __restrict__ Abase,
                                                const u16* __restrict__ Wtbase,
                                                const int* __restrict__ flat_idx,
                                                const float* __restrict__ cosb,
                                                const float* __restrict__ sinb,
                                                u16* __restrict__ Qb, u16* __restrict__ Kb,
                                                u16* __restrict__ Vb) {
    __shared__ __align__(16) u16 As[128 * 32];
    __shared__ __align__(16) u16 Bs[128 * 32];
    const int K = 1024, N = 3072;
    int e = blockIdx.z;
    const u16* A  = Abase + (size_t)(e >> 1) * 1024 * K;
    const u16* Wt = Wtbase + (size_t)flat_idx[e] * N * K;
    int m0 = blockIdx.y * 128, n0 = blockIdx.x * 128;
    int t = threadIdx.x, lane = t & 63, w = t >> 6;
    int g = lane >> 4, c = lane & 15;
    int wm = (w >> 1) * 64, wn = (w & 1) * 64;

    GEMM_CORE(A, Wt, K)

    int col0 = n0 + wn;                 // multiple of 64
    int sb = m0 + wm + g * 4;
    if (col0 < 2048) {
        bool isq = col0 < 1024;
        u16* dst = isq ? Qb : Kb;
        int h = (col0 & 1023) >> 6;
        const float scl = isq ? 0.125f * 1.44269504f : 1.0f;
#pragma unroll
        for (int ti = 0; ti < 4; ++ti)
#pragma unroll
            for (int i = 0; i < 4; ++i) {
                int s = sb + ti * 16 + i;
                size_t ob = ((size_t)(e * 1024) + s) * 1024 + h * 64;
#pragma unroll
                for (int tj = 0; tj < 2; ++tj) {
                    int d = tj * 16 + c;
                    float x1 = acc[ti][tj][i], x2 = acc[ti][tj + 2][i];
                    float c1 = cosb[s * 64 + d],      s1 = sinb[s * 64 + d];
                    float c2 = cosb[s * 64 + d + 32], s2 = sinb[s * 64 + d + 32];
                    dst[ob + d]      = f2bf((x1 * c1 - x2 * s1) * scl);
                    dst[ob + d + 32] = f2bf((x2 * c2 + x1 * s2) * scl);
                }
            }
    } else {
        int vcol = col0 - 2048;
#pragma unroll
        for (int ti = 0; ti < 4; ++ti)
#pragma unroll
            for (int tj = 0; tj < 4; ++tj)
#pragma unroll
                for (int i = 0; i < 4; ++i)
                    Vb[((size_t)(e * 1024) + sb + ti * 16 + i) * 1024 + vcol + tj * 16 + c] = f2bf(acc[ti][tj][i]);
    }
}

// ---------------- Wgu GEMM (interleaved columns) + fused SiLU*up epilogue ----------------
__global__ __launch_bounds__(256) void gemm_wgu_silu(const u16* __restrict__ Abase,
                                                     const u16* __restrict__ Wtbase,
                                                     u16* __restrict__ act,
                                                     const int* __restrict__ flat_idx) {
    __shared__ __align__(16) u16 As[128 * 32];
    __shared__ __align__(16) u16 Bs[128 * 32];
    const int K = 1024, N = 1536;
    int e = blockIdx.z;
    const u16* A  = Abase + (size_t)e * 1024 * K;
    const u16* Wt = Wtbase + (size_t)flat_idx[e] * N * K;
    int m0 = blockIdx.y * 128, n0 = blockIdx.x * 128;
    int t = threadIdx.x, lane = t & 63, w = t >> 6;
    int g = lane >> 4, c = lane & 15;
    int wm = (w >> 1) * 64, wn = (w & 1) * 64;

    GEMM_CORE(A, Wt, K)

    int col0 = n0 + wn;
    int oc0 = (col0 >> 1) + c;          // act col for tj pair (0,1); +16 for (2,3)
    int sb = m0 + wm + g * 4;
#pragma unroll
    for (int ti = 0; ti < 4; ++ti)
#pragma unroll
        for (int i = 0; i < 4; ++i) {
            size_t rb = ((size_t)(e * 1024) + sb + ti * 16 + i) * 768;
#pragma unroll
            for (int pr = 0; pr < 2; ++pr) {
                float gt = acc[ti][pr * 2][i];
                float up = acc[ti][pr * 2 + 1][i];
                act[rb + oc0 + pr * 16] = f2bf(gt / (1.f + __expf(-gt)) * up);
            }
        }
}

// ---------------- V transpose: Vb[e][s][d] -> Vtg[e][h][d=64][kv=1024] ----------------
__global__ __launch_bounds__(256) void vtrans(const u16* __restrict__ Vb, u16* __restrict__ Vtg) {
    __shared__ __align__(16) u16 tile[64 * 72];
    int s0 = blockIdx.x * 64;
    int eh = blockIdx.y;
    int e = eh >> 4, h = eh & 15;
    int t = threadIdx.x;
#pragma unroll
    for (int it = 0; it < 2; ++it) {
        int p = it * 256 + t;
        int sr = p >> 3, ds = p & 7;
        u16x8 v = *(const u16x8*)&Vb[((size_t)(e * 1024) + s0 + sr) * 1024 + h * 64 + ds * 8];
        *(u16x8*)&tile[sr * 72 + ds * 8] = v;
    }
    __syncthreads();
#pragma unroll
    for (int it = 0; it < 2; ++it) {
        int p = it * 256 + t;
        int d = p >> 3, ks = p & 7;
        u16x8 o;
#pragma unroll
        for (int jj = 0; jj < 8; ++jj) o[jj] = tile[(ks * 8 + jj) * 72 + d];
        *(u16x8*)&Vtg[((size_t)((e * 16 + h) * 64) + d) * 1024 + s0 + ks * 8] = o;
    }
}

// ---------------- MFMA flash attention (S^T = K Q^T; register P) ----------------
__global__ __launch_bounds__(256) void attn_mfma(const u16* __restrict__ Qb, const u16* __restrict__ Kb,
                                                 const u16* __restrict__ Vtg, u16* __restrict__ ctx) {
    __shared__ __align__(16) u16 Ks[64 * 64];
    __shared__ __align__(16) u16 Vt[64 * 64];
    int e = blockIdx.x, h = blockIdx.y, qt = blockIdx.z;
    int t = threadIdx.x, lane = t & 63, w = t >> 6;
    int g = lane >> 4, c = lane & 15;
    int q0 = qt * 64 + w * 16;

    s8v qf[2];
#pragma unroll
    for (int ks = 0; ks < 2; ++ks)
        qf[ks] = *(const s8v*)&Qb[((size_t)(e * 1024) + q0 + c) * 1024 + h * 64 + ks * 32 + g * 8];

    f4v O[4];
#pragma unroll
    for (int tj = 0; tj < 4; ++tj) O[tj] = (f4v){0.f, 0.f, 0.f, 0.f};
    f4v liacc = (f4v){0.f, 0.f, 0.f, 0.f};
    const s4v vone = {(short)0x3F80, (short)0x3F80, (short)0x3F80, (short)0x3F80};

    for (int kt = 0; kt < 16; ++kt) {
#pragma unroll
        for (int it = 0; it < 2; ++it) {
            int p = it * 256 + w * 64 + lane;
            int row = p >> 3, ss = p & 7;
            GLDS16(Kb + ((size_t)(e * 1024 + kt * 64 + row)) * 1024 + h * 64 + (ss ^ (row & 7)) * 8,
                   Ks + (size_t)(it * 256 + w * 64) * 8);
            GLDS16(Vtg + ((size_t)((e * 16 + h) * 64 + row)) * 1024 + kt * 64 + (ss ^ (row & 7)) * 8,
                   Vt + (size_t)(it * 256 + w * 64) * 8);
        }
        __syncthreads();

        f4v st[4];
#pragma unroll
        for (int tj = 0; tj < 4; ++tj) st[tj] = (f4v){0.f, 0.f, 0.f, 0.f};
#pragma unroll
        for (int ks = 0; ks < 2; ++ks)
#pragma unroll
            for (int tj = 0; tj < 4; ++tj) {
                int kvl = tj * 16 + c;
                s8v kf = *(const s8v*)&Ks[kvl * 64 + (((ks * 4 + g) ^ (kvl & 7)) * 8)];
                st[tj] = __builtin_amdgcn_mfma_f32_16x16x32_bf16(kf, qf[ks], st[tj], 0, 0, 0);
            }

        s4v pf[4];
#pragma unroll
        for (int tj = 0; tj < 4; ++tj) {
            float p0 = __builtin_amdgcn_exp2f(st[tj][0]);
            float p1 = __builtin_amdgcn_exp2f(st[tj][1]);
            float p2 = __builtin_amdgcn_exp2f(st[tj][2]);
            float p3 = __builtin_amdgcn_exp2f(st[tj][3]);
            union { unsigned u[2]; s4v v; } pu;
            pu.u[0] = pk2(p0, p1);
            pu.u[1] = pk2(p2, p3);
            pf[tj] = pu.v;
        }

#pragma unroll
        for (int tjC = 0; tjC < 4; ++tjC) {
            liacc = __builtin_amdgcn_mfma_f32_16x16x16bf16_1k(pf[tjC], vone, liacc, 0, 0, 0);
#pragma unroll
            for (int tjd = 0; tjd < 4; ++tjd) {
                int d = tjd * 16 + c;
                int sd = tjC * 2 + (g >> 1);
                s4v vf = *(const s4v*)&Vt[d * 64 + ((sd ^ (d & 7)) * 8) + (g & 1) * 4];
                O[tjd] = __builtin_amdgcn_mfma_f32_16x16x16bf16_1k(pf[tjC], vf, O[tjd], 0, 0, 0);
            }
        }
        __syncthreads();
    }
#pragma unroll
    for (int i = 0; i < 4; ++i) {
        float linv = 1.0f / liacc[i];
        size_t rbase = ((size_t)(e * 1024) + q0 + g * 4 + i) * 1024 + h * 64;
#pragma unroll
        for (int tjd = 0; tjd < 4; ++tjd)
            ctx[rbase + tjd * 16 + c] = f2bf(O[tjd][i] * linv);
    }
}

// ---------------- xnb = bf16(rmsnorm(hb[b] + aob)) ----------------
__global__ void add_rmsnorm(const u16* __restrict__ hb, const u16* __restrict__ aob,
                            u16* __restrict__ xnb) {
    int row = blockIdx.x;          // e*SEQ + s
    int e = row >> 10;
    int b = e >> 1;
    int s = row & 1023;
    const u16* xr = hb + (((size_t)b * SEQ_ + s) << 10);
    const u16* ar = aob + ((size_t)row << 10);
    u16* o = xnb + ((size_t)row << 10);
    int t = threadIdx.x;
    u16x4 xv = *(const u16x4*)&xr[t * 4];
    u16x4 av = *(const u16x4*)&ar[t * 4];
    float v[4];
    float ss = 0.f;
#pragma unroll
    for (int i = 0; i < 4; ++i) {
        v[i] = bf2f(xv[i]) + bf2f(av[i]);
        ss += v[i] * v[i];
    }
    for (int off = 32; off >= 1; off >>= 1) ss += __shfl_down(ss, off, 64);
    __shared__ float wred[4];
    if ((t & 63) == 0) wred[t >> 6] = ss;
    __syncthreads();
    float tot = wred[0] + wred[1] + wred[2] + wred[3];
    float scale = rsqrtf(tot * (1.0f / 1024.0f) + EPS_);
    u16x4 ov;
#pragma unroll
    for (int i = 0; i < 4; ++i) ov[i] = f2bf(v[i] * scale);
    *(u16x4*)&o[t * 4] = ov;
}

// ---------------- out[b] = sum_j w_e * rmsnorm(xn[e] + mlp[e]) ----------------
__global__ void final_kernel(const u16* __restrict__ xnb, const u16* __restrict__ mlpb,
                             const float* __restrict__ flat_w, float* __restrict__ out) {
    int row = blockIdx.x;           // b*SEQ + s
    int b = row >> 10;
    int s = row & 1023;
    int t = threadIdx.x;
    __shared__ float wred[4];
    float res[4] = {0.f, 0.f, 0.f, 0.f};
    for (int j = 0; j < 2; ++j) {
        int e = 2 * b + j;
        size_t off = (((size_t)e * SEQ_ + s) << 10);
        u16x4 xv = *(const u16x4*)&xnb[off + t * 4];
        u16x4 mv = *(const u16x4*)&mlpb[off + t * 4];
        float v[4];
        float ss = 0.f;
#pragma unroll
        for (int i = 0; i < 4; ++i) {
            v[i] = bf2f(xv[i]) + bf2f(mv[i]);
            ss += v[i] * v[i];
        }
        for (int off2 = 32; off2 >= 1; off2 >>= 1) ss += __shfl_down(ss, off2, 64);
        if ((t & 63) == 0) wred[t >> 6] = ss;
        __syncthreads();
        float tot = wred[0] + wred[1] + wred[2] + wred[3];
        float scale = rsqrtf(tot * (1.0f / 1024.0f) + EPS_);
        float wgt = flat_w[e];
#pragma unroll
        for (int i = 0; i < 4; ++i) res[i] += wgt * v[i] * scale;
        __syncthreads();
    }
    float* o = out + ((size_t)row << 10);
    *(float4*)&o[t * 4] = make_float4(res[0], res[1], res[2], res[3]);
}

extern "C" void kernel_launch(void* const* d_in, const int* in_sizes, int n_in,
                              void* d_out, int out_size, void* d_ws, size_t ws_size,
                              hipStream_t stream) {
    const float* hidden = (const float*)d_in[0];
    const float* cosb   = (const float*)d_in[1];
    const float* sinb   = (const float*)d_in[2];
    const float* Wr     = (const float*)d_in[3];
    const float* temp   = (const float*)d_in[4];
    const float* Wqkv   = (const float*)d_in[5];
    const float* Wo     = (const float*)d_in[6];
    const float* Wgu    = (const float*)d_in[7];
    const float* Wd     = (const float*)d_in[8];
    float* out = (float*)d_out;
    float* out_logits = out + (size_t)B_ * SEQ_ * D_;

    char* base = (char*)d_ws;
    int*   flat_idx = (int*)base;
    float* flat_w   = (float*)(base + 128);
    float* routeP   = (float*)(base + 4096);          // 512 KB
    size_t off = (size_t)1 << 20;
    u16* WqkvT = (u16*)(base + off); off += (size_t)8 * 3072 * 1024 * 2;
    u16* WoT   = (u16*)(base + off); off += (size_t)8 * 1024 * 1024 * 2;
    u16* WguT  = (u16*)(base + off); off += (size_t)8 * 1536 * 1024 * 2;
    u16* WdT   = (u16*)(base + off); off += (size_t)8 * 1024 * 768 * 2;
    u16* hb    = (u16*)(base + off); off += (size_t)4 * 1024 * 1024 * 2;
    u16* Qb    = (u16*)(base + off); off += (size_t)8 * 1024 * 1024 * 2;
    u16* Kb    = (u16*)(base + off); off += (size_t)8 * 1024 * 1024 * 2;
    u16* Vb    = (u16*)(base + off); off += (size_t)8 * 1024 * 1024 * 2;
    u16* Vtg   = (u16*)(base + off); off += (size_t)8 * 1024 * 1024 * 2;
    u16* ctxb  = (u16*)(base + off); off += (size_t)8 * 1024 * 1024 * 2;
    u16* aob   = (u16*)(base + off); off += (size_t)8 * 1024 * 1024 * 2;
    u16* xnb   = (u16*)(base + off); off += (size_t)8 * 1024 * 1024 * 2;
    u16* actb  = (u16*)(base + off); off += (size_t)8 * 1024 * 768 * 2;
    u16* mlpb  = (u16*)(base + off); off += (size_t)8 * 1024 * 1024 * 2;

    route1<<<dim3(4, 32), 256, 0, stream>>>(hidden, routeP, hb);
    route2<<<4, 256, 0, stream>>>(routeP, Wr, temp, out_logits, flat_idx, flat_w);
    wtrans_all<<<12800, 256, 0, stream>>>(Wqkv, Wo, Wgu, Wd, WqkvT, WoT, WguT, WdT);

    gemm_qkv<<<dim3(24, 8, 8), 256, 0, stream>>>(hb, WqkvT, flat_idx, cosb, sinb, Qb, Kb, Vb);
    vtrans<<<dim3(16, 128), 256, 0, stream>>>(Vb, Vtg);
    attn_mfma<<<dim3(8, 16, 16), 256, 0, stream>>>(Qb, Kb, Vtg, ctxb);
    gemm_bf16<<<dim3(8, 8, 8), 256, 0, stream>>>(ctxb, WoT, aob, flat_idx, 1024, 1024, 1024, 1);
    add_rmsnorm<<<NE_ * SEQ_, 256, 0, stream>>>(hb, aob, xnb);
    gemm_wgu_silu<<<dim3(12, 8, 8), 256, 0, stream>>>(xnb, WguT, actb, flat_idx);
    gemm_bf16<<<dim3(8, 8, 8), 256, 0, stream>>>(actb, WdT, mlpb, flat_idx, 1024, 1024, 768, 1);
    final_kernel<<<B_ * SEQ_, 256, 0, stream>>>(xnb, mlpb, flat_w, out);
}